// Round 13
// baseline (1356.222 us; speedup 1.0000x reference)
//
#include <hip/hip_runtime.h>
#include <cstdint>
#include <cstddef>

// Problem constants
constexpr int Bc   = 2;
constexpr int Sc   = 2048;
constexpr int Dm   = 768;
constexpr int Hc   = 12;
constexpr int DI   = 1536;
constexpr int NST  = 16;
constexpr int DTR  = 48;
constexpr int CAP  = 256;
constexpr int DF   = 3072;
constexpr int M_   = Bc * Sc;        // 4096
constexpr int NQ   = Bc * Hc * Sc;   // 49152
constexpr int NCH  = 4;
constexpr size_t TOK = (size_t)M_ * Dm;   // 3,145,728

typedef __attribute__((ext_vector_type(8))) short bf16x8;
typedef __attribute__((ext_vector_type(4))) float f32x4;

__device__ __forceinline__ float apply_act(float v, int act) {
    switch (act) {
        case 1: return (v > 20.f) ? v : log1pf(__expf(v));
        case 2: return 1.f / (1.f + __expf(-v));
        case 3: return fmaxf(v, 0.f);
        case 4: return 0.5f * v * (1.f + erff(v * 0.70710678118654752f));
        default: return v;
    }
}
__device__ __forceinline__ short f2bf(float x) {   // RNE
    unsigned u = __float_as_uint(x);
    unsigned r = u + 0x7FFFu + ((u >> 16) & 1u);
    return (short)(r >> 16);
}
__device__ __forceinline__ float bf2f(short h) {
    return __uint_as_float(((unsigned)(unsigned short)h) << 16);
}
__device__ __forceinline__ void split8v(const float* v, bf16x8& hi, bf16x8& lo) {
#pragma unroll
    for (int j = 0; j < 8; ++j) {
        short hs = f2bf(v[j]);
        hi[j] = hs;
        lo[j] = f2bf(v[j] - bf2f(hs));
    }
}

// ---------------------------------------------------------------------------
// Weight pre-swizzle: fp32 [K x N] -> bf16 hi/lo in MFMA B-fragment order.
__global__ __launch_bounds__(256) void wswz_kernel(
    const float* __restrict__ W, short* __restrict__ Wh, short* __restrict__ Wl,
    int K, int N, int Kpad, int Npad)
{
    int id = blockIdx.x * 256 + threadIdx.x;
    if (id >= Kpad * Npad) return;
    int n = id % Npad, k = id / Npad;
    float v = (k < K && n < N) ? W[(size_t)k * N + n] : 0.f;
    short h = f2bf(v);
    short l = f2bf(v - bf2f(h));
    int NT = Npad >> 4;
    size_t off = ((((size_t)(k >> 5) * NT + (n >> 4)) * 4 + ((k >> 3) & 3)) * 16
                  + (n & 15)) * 8 + (k & 7);
    Wh[off] = h; Wl[off] = l;
}

// ---------------------------------------------------------------------------
// bf16x3 MFMA GEMM: fp32 A (row-major, lda), pre-swizzled bf16 B hi/lo.
// C = act(acc*C + A@W + bias). Tile 128x128x32, 4 waves of 64x64.
template <int ID>
__global__ __launch_bounds__(256, 2) void gemm_bf3(
    const float* __restrict__ A, int lda,
    const short* __restrict__ Bh, const short* __restrict__ Bl, int ntiles,
    const float* __restrict__ bias,
    float* __restrict__ C,
    int M, int N, int K, int act, int accflag)
{
    __shared__ __attribute__((aligned(16))) short AhS[4096];
    __shared__ __attribute__((aligned(16))) short AlS[4096];
    const int tid = threadIdx.x, lane = tid & 63, wid = tid >> 6;
    const int wm = wid >> 1, wn = wid & 1;
    const int bm = blockIdx.y * 128, bn = blockIdx.x * 128;

    f32x4 acc[4][4];
#pragma unroll
    for (int i = 0; i < 4; ++i)
#pragma unroll
        for (int j = 0; j < 4; ++j) acc[i][j] = (f32x4){0.f, 0.f, 0.f, 0.f};

    const int ksteps = (K + 31) >> 5;
    for (int ks = 0; ks < ksteps; ++ks) {
        const int k0 = ks << 5;
        bf16x8 bh[4], bl[4];
        const size_t bbase = ((size_t)ks * ntiles + (bn >> 4) + wn * 4) * 512
                           + (size_t)lane * 8;
#pragma unroll
        for (int t = 0; t < 4; ++t) {
            bh[t] = *(const bf16x8*)&Bh[bbase + (size_t)t * 512];
            bl[t] = *(const bf16x8*)&Bl[bbase + (size_t)t * 512];
        }
#pragma unroll
        for (int i = 0; i < 2; ++i) {
            int c = i * 256 + tid;          // chunk 0..511
            int l = c & 63;
            int m = ((c >> 6) << 4) + (l & 15);
            int q = l >> 4;
            int kk = k0 + q * 8;
            short4 h0, l0, h1, l1;
            if (kk + 8 <= K) {
                const float* ap = A + (size_t)(bm + m) * lda + kk;
                float4 f0 = *(const float4*)ap;
                float4 f1 = *(const float4*)(ap + 4);
                h0.x = f2bf(f0.x); l0.x = f2bf(f0.x - bf2f(h0.x));
                h0.y = f2bf(f0.y); l0.y = f2bf(f0.y - bf2f(h0.y));
                h0.z = f2bf(f0.z); l0.z = f2bf(f0.z - bf2f(h0.z));
                h0.w = f2bf(f0.w); l0.w = f2bf(f0.w - bf2f(h0.w));
                h1.x = f2bf(f1.x); l1.x = f2bf(f1.x - bf2f(h1.x));
                h1.y = f2bf(f1.y); l1.y = f2bf(f1.y - bf2f(h1.y));
                h1.z = f2bf(f1.z); l1.z = f2bf(f1.z - bf2f(h1.z));
                h1.w = f2bf(f1.w); l1.w = f2bf(f1.w - bf2f(h1.w));
            } else {
                h0 = short4{0,0,0,0}; l0 = h0; h1 = h0; l1 = h0;
            }
            int off = c * 8;
            *(short4*)&AhS[off]     = h0;
            *(short4*)&AhS[off + 4] = h1;
            *(short4*)&AlS[off]     = l0;
            *(short4*)&AlS[off + 4] = l1;
        }
        __syncthreads();
        bf16x8 ah[4], al[4];
#pragma unroll
        for (int t = 0; t < 4; ++t) {
            int ai = ((wm * 4 + t) * 64 + lane) * 8;
            ah[t] = *(const bf16x8*)&AhS[ai];
            al[t] = *(const bf16x8*)&AlS[ai];
        }
#pragma unroll
        for (int im = 0; im < 4; ++im)
#pragma unroll
            for (int in = 0; in < 4; ++in) {
                acc[im][in] = __builtin_amdgcn_mfma_f32_16x16x32_bf16(ah[im], bh[in], acc[im][in], 0, 0, 0);
                acc[im][in] = __builtin_amdgcn_mfma_f32_16x16x32_bf16(ah[im], bl[in], acc[im][in], 0, 0, 0);
                acc[im][in] = __builtin_amdgcn_mfma_f32_16x16x32_bf16(al[im], bh[in], acc[im][in], 0, 0, 0);
            }
        __syncthreads();
    }

    const int qrow = (lane >> 4) * 4;
#pragma unroll
    for (int im = 0; im < 4; ++im) {
        int rowb = bm + wm * 64 + im * 16 + qrow;
#pragma unroll
        for (int in = 0; in < 4; ++in) {
            int col = bn + wn * 64 + in * 16 + (lane & 15);
            if (col < N) {
#pragma unroll
                for (int r = 0; r < 4; ++r) {
                    size_t cidx = (size_t)(rowb + r) * N + col;
                    float v = acc[im][in][r];
                    if (accflag) v += C[cidx];
                    if (bias) v += bias[col];
                    C[cidx] = apply_act(v, act);
                }
            }
        }
    }
}

// ---------------------------------------------------------------------------
// Split-K variant (r9-verified): blockIdx.z selects a K-partition.
template <int ID>
__global__ __launch_bounds__(256, 2) void gemm_bf3_pk(
    const float* __restrict__ A, int lda,
    const short* __restrict__ Bh, const short* __restrict__ Bl, int ntiles,
    float* __restrict__ Cpart,
    int M, int N, int Kpart)
{
    __shared__ __attribute__((aligned(16))) short AhS[4096];
    __shared__ __attribute__((aligned(16))) short AlS[4096];
    const int tid = threadIdx.x, lane = tid & 63, wid = tid >> 6;
    const int wm = wid >> 1, wn = wid & 1;
    const int bm = blockIdx.y * 128, bn = blockIdx.x * 128;
    const int kofs = blockIdx.z * Kpart;          // element offset into K
    const int kz0  = kofs >> 5;                   // global k-step base

    f32x4 acc[4][4];
#pragma unroll
    for (int i = 0; i < 4; ++i)
#pragma unroll
        for (int j = 0; j < 4; ++j) acc[i][j] = (f32x4){0.f, 0.f, 0.f, 0.f};

    const int ksteps = Kpart >> 5;
    for (int ks = 0; ks < ksteps; ++ks) {
        const int k0 = ks << 5;
        bf16x8 bh[4], bl[4];
        const size_t bbase = ((size_t)(kz0 + ks) * ntiles + (bn >> 4) + wn * 4) * 512
                           + (size_t)lane * 8;
#pragma unroll
        for (int t = 0; t < 4; ++t) {
            bh[t] = *(const bf16x8*)&Bh[bbase + (size_t)t * 512];
            bl[t] = *(const bf16x8*)&Bl[bbase + (size_t)t * 512];
        }
#pragma unroll
        for (int i = 0; i < 2; ++i) {
            int c = i * 256 + tid;          // chunk 0..511
            int l = c & 63;
            int m = ((c >> 6) << 4) + (l & 15);
            int q = l >> 4;
            int kk = kofs + k0 + q * 8;     // always in-range (K = parts*Kpart)
            const float* ap = A + (size_t)(bm + m) * lda + kk;
            float4 f0 = *(const float4*)ap;
            float4 f1 = *(const float4*)(ap + 4);
            short4 h0, l0, h1, l1;
            h0.x = f2bf(f0.x); l0.x = f2bf(f0.x - bf2f(h0.x));
            h0.y = f2bf(f0.y); l0.y = f2bf(f0.y - bf2f(h0.y));
            h0.z = f2bf(f0.z); l0.z = f2bf(f0.z - bf2f(h0.z));
            h0.w = f2bf(f0.w); l0.w = f2bf(f0.w - bf2f(h0.w));
            h1.x = f2bf(f1.x); l1.x = f2bf(f1.x - bf2f(h1.x));
            h1.y = f2bf(f1.y); l1.y = f2bf(f1.y - bf2f(h1.y));
            h1.z = f2bf(f1.z); l1.z = f2bf(f1.z - bf2f(h1.z));
            h1.w = f2bf(f1.w); l1.w = f2bf(f1.w - bf2f(h1.w));
            int off = c * 8;
            *(short4*)&AhS[off]     = h0;
            *(short4*)&AhS[off + 4] = h1;
            *(short4*)&AlS[off]     = l0;
            *(short4*)&AlS[off + 4] = l1;
        }
        __syncthreads();
        bf16x8 ah[4], al[4];
#pragma unroll
        for (int t = 0; t < 4; ++t) {
            int ai = ((wm * 4 + t) * 64 + lane) * 8;
            ah[t] = *(const bf16x8*)&AhS[ai];
            al[t] = *(const bf16x8*)&AlS[ai];
        }
#pragma unroll
        for (int im = 0; im < 4; ++im)
#pragma unroll
            for (int in = 0; in < 4; ++in) {
                acc[im][in] = __builtin_amdgcn_mfma_f32_16x16x32_bf16(ah[im], bh[in], acc[im][in], 0, 0, 0);
                acc[im][in] = __builtin_amdgcn_mfma_f32_16x16x32_bf16(ah[im], bl[in], acc[im][in], 0, 0, 0);
                acc[im][in] = __builtin_amdgcn_mfma_f32_16x16x32_bf16(al[im], bh[in], acc[im][in], 0, 0, 0);
            }
        __syncthreads();
    }

    float* Cp = Cpart + (size_t)blockIdx.z * M * N;
    const int qrow = (lane >> 4) * 4;
#pragma unroll
    for (int im = 0; im < 4; ++im) {
        int rowb = bm + wm * 64 + im * 16 + qrow;
#pragma unroll
        for (int in = 0; in < 4; ++in) {
            int col = bn + wn * 64 + in * 16 + (lane & 15);
#pragma unroll
            for (int r = 0; r < 4; ++r)
                Cp[(size_t)(rowb + r) * N + col] = acc[im][in][r];
        }
    }
}

// Combine split-K partials: C = act(sum_p parts[p] + bias).
__global__ __launch_bounds__(256) void pkreduce_kernel(
    const float* __restrict__ parts, int nparts, int MN, int N,
    const float* __restrict__ bias, float* __restrict__ C, int act)
{
    int id = blockIdx.x * 256 + threadIdx.x;
    if (id >= MN) return;
    float s = 0.f;
    for (int p = 0; p < nparts; ++p) s += parts[(size_t)p * MN + id];
    s += bias[id % N];
    C[id] = apply_act(s, act);
}

// ---------------------------------------------------------------------------
// fp32 scalar GEMM (router projection only — selection-critical).
// 64x64 tiles (r10); per-output sequential-k fmaf order unchanged.
template <int ID>
__global__ __launch_bounds__(256, 2) void gemm_kernel(
    const float* __restrict__ A, int lda,
    const float* __restrict__ W,
    const float* __restrict__ bias,
    float* __restrict__ C,
    int M, int N, int K, int act, int accflag)
{
    __shared__ float As[16][68];
    __shared__ float Bs[16][68];
    const int tid = threadIdx.x;
    const int bm = blockIdx.y * 64;
    const int bn = blockIdx.x * 64;
    const int tx = tid & 15, ty = tid >> 4;
    float acc[4][4];
#pragma unroll
    for (int i = 0; i < 4; ++i)
#pragma unroll
        for (int j = 0; j < 4; ++j) acc[i][j] = 0.f;
    for (int k0 = 0; k0 < K; k0 += 16) {
        {
            int row = tid >> 2;            // 0..63
            int kc = (tid & 3) * 4;
            const float* ap = A + (size_t)(bm + row) * lda + (k0 + kc);
            float4 v = *(const float4*)ap;
            As[kc + 0][row] = v.x; As[kc + 1][row] = v.y;
            As[kc + 2][row] = v.z; As[kc + 3][row] = v.w;
        }
        {
            int row = tid >> 4;            // 0..15 (k)
            int col = (tid & 15) * 4;
            int gn = bn + col;
            const float* wp = W + (size_t)(k0 + row) * N + gn;
            float4 v;
            if (gn + 3 < N) v = *(const float4*)wp;
            else {
                v.x = (gn + 0 < N) ? wp[0] : 0.f;
                v.y = (gn + 1 < N) ? wp[1] : 0.f;
                v.z = (gn + 2 < N) ? wp[2] : 0.f;
                v.w = (gn + 3 < N) ? wp[3] : 0.f;
            }
            *(float4*)&Bs[row][col] = v;
        }
        __syncthreads();
#pragma unroll
        for (int kk = 0; kk < 16; ++kk) {
            float a[4], b[4];
            *(float4*)&a[0] = *(const float4*)&As[kk][ty * 4];
            *(float4*)&b[0] = *(const float4*)&Bs[kk][tx * 4];
#pragma unroll
            for (int i = 0; i < 4; ++i)
#pragma unroll
                for (int j = 0; j < 4; ++j)
                    acc[i][j] = fmaf(a[i], b[j], acc[i][j]);
        }
        __syncthreads();
    }
#pragma unroll
    for (int ii = 0; ii < 4; ++ii) {
        int row = bm + ty * 4 + ii;
#pragma unroll
        for (int jj = 0; jj < 4; ++jj) {
            int col = bn + tx * 4 + jj;
            if (col < N) {
                size_t cidx = (size_t)row * N + col;
                float v = acc[ii][jj];
                if (accflag) v += C[cidx];
                if (bias) v += bias[col];
                C[cidx] = apply_act(v, act);
            }
        }
    }
}

// ---------------------------------------------------------------------------
// delta = softplus(dbc[:, :48] @ dt_w + dt_b), fp32 (r11-verified).
__global__ __launch_bounds__(256) void delta_kernel(
    const float* __restrict__ dbc, const float* __restrict__ dt_w,
    const float* __restrict__ dt_b, float* __restrict__ delta)
{
    __shared__ float dlow[48];
    const int m = blockIdx.x;
    const int tid = threadIdx.x;
    if (tid < 48) dlow[tid] = dbc[(size_t)m * 80 + tid];
    __syncthreads();
    float acc[6];
#pragma unroll
    for (int i = 0; i < 6; ++i) acc[i] = 0.f;
    for (int k = 0; k < 48; ++k) {
        float a = dlow[k];
        const float* wr = dt_w + (size_t)k * DI;
#pragma unroll
        for (int i = 0; i < 6; ++i)
            acc[i] = fmaf(a, wr[tid + i * 256], acc[i]);
    }
    float* dp = delta + (size_t)m * DI;
#pragma unroll
    for (int i = 0; i < 6; ++i) {
        int n = tid + i * 256;
        float v = acc[i] + dt_b[n];
        dp[n] = (v > 20.f) ? v : log1pf(__expf(v));
    }
}

// ---------------------------------------------------------------------------
__global__ __launch_bounds__(256) void ln_kernel(
    const float* __restrict__ x, const float* __restrict__ w,
    const float* __restrict__ b, float* __restrict__ out)
{
    const int row = blockIdx.x, tid = threadIdx.x;
    const float* xp = x + (size_t)row * Dm;
    float v0 = xp[tid], v1 = xp[tid + 256], v2 = xp[tid + 512];
    float s1 = v0 + v1 + v2;
    float s2 = v0 * v0 + v1 * v1 + v2 * v2;
#pragma unroll
    for (int off = 32; off; off >>= 1) {
        s1 += __shfl_down(s1, off, 64);
        s2 += __shfl_down(s2, off, 64);
    }
    __shared__ float r1[4], r2[4];
    int wid = tid >> 6, lane = tid & 63;
    if (lane == 0) { r1[wid] = s1; r2[wid] = s2; }
    __syncthreads();
    s1 = r1[0] + r1[1] + r1[2] + r1[3];
    s2 = r2[0] + r2[1] + r2[2] + r2[3];
    float mu = s1 * (1.f / 768.f);
    float var = s2 * (1.f / 768.f) - mu * mu;
    float rstd = rsqrtf(var + 1e-5f);
    float* op = out + (size_t)row * Dm;
    op[tid]       = (v0 - mu) * rstd * w[tid]       + b[tid];
    op[tid + 256] = (v1 - mu) * rstd * w[tid + 256] + b[tid + 256];
    op[tid + 512] = (v2 - mu) * rstd * w[tid + 512] + b[tid + 512];
}

// ---------------------------------------------------------------------------
__global__ __launch_bounds__(256) void rope_kernel(float* __restrict__ qkv)
{
    int id = blockIdx.x * 256 + threadIdx.x;
    int i = id & 31;
    int h = (id >> 5) % Hc;
    int r = id / (32 * Hc);
    int s = r & (Sc - 1);
    float inv = powf(10000.f, -(float)(2 * i) * (1.f / 64.f));
    float f = (float)s * inv;
    float sn, cs;
    sincosf(f, &sn, &cs);
    float* base = qkv + (size_t)r * 2304 + h * 64 + i;
    float q1 = base[0], q2 = base[32];
    base[0]  = q1 * cs - q2 * sn;
    base[32] = q1 * sn + q2 * cs;
    float* kb = base + Dm;
    float k1 = kb[0], k2 = kb[32];
    kb[0]  = k1 * cs - k2 * sn;
    kb[32] = k1 * sn + k2 * cs;
}

// ---------------------------------------------------------------------------
// K split: post-RoPE K section of qkv -> bf16 hi/lo planes [M_, 768].
__global__ __launch_bounds__(256) void ksplit_kernel(
    const float* __restrict__ qkv, short* __restrict__ kph, short* __restrict__ kpl)
{
    int id = blockIdx.x * 256 + threadIdx.x;   // M_*96 total
    int r = id / 96;
    int c = (id - r * 96) * 8;
    const float* src = qkv + (size_t)r * 2304 + Dm + c;
    float4 f0 = *(const float4*)src;
    float4 f1 = *(const float4*)(src + 4);
    short4 h0, l0, h1, l1;
    h0.x = f2bf(f0.x); l0.x = f2bf(f0.x - bf2f(h0.x));
    h0.y = f2bf(f0.y); l0.y = f2bf(f0.y - bf2f(h0.y));
    h0.z = f2bf(f0.z); l0.z = f2bf(f0.z - bf2f(h0.z));
    h0.w = f2bf(f0.w); l0.w = f2bf(f0.w - bf2f(h0.w));
    h1.x = f2bf(f1.x); l1.x = f2bf(f1.x - bf2f(h1.x));
    h1.y = f2bf(f1.y); l1.y = f2bf(f1.y - bf2f(h1.y));
    h1.z = f2bf(f1.z); l1.z = f2bf(f1.z - bf2f(h1.z));
    h1.w = f2bf(f1.w); l1.w = f2bf(f1.w - bf2f(h1.w));
    short* dh = kph + (size_t)r * 768 + c;
    short* dl = kpl + (size_t)r * 768 + c;
    *(short4*)dh = h0; *(short4*)(dh + 4) = h1;
    *(short4*)dl = l0; *(short4*)(dl + 4) = l1;
}

// ---------------------------------------------------------------------------
// V transpose+split: qkv V section -> V^T bf16 hi/lo planes [bh, d(64), Sc].
// LDS 64x65 tile transpose (r6/r7-verified correct).
__global__ __launch_bounds__(256) void vtrans_kernel(
    const float* __restrict__ qkv, short* __restrict__ vth, short* __restrict__ vtl)
{
    __shared__ float tile[64][65];
    const int blk = blockIdx.x;              // Bc*Hc*32
    const int bh = blk >> 5;
    const int st = blk & 31;
    const int b = bh / Hc, h = bh % Hc;
    const int s0 = st * 64;
    const int tid = threadIdx.x;
    const int lc = tid & 63;                 // lane within 64
    const int grp = tid >> 6;                // 0..3
    const float* src = qkv + ((size_t)(b * Sc + s0 + grp * 16)) * 2304
                     + 2 * Dm + h * 64 + lc;
#pragma unroll
    for (int i = 0; i < 16; ++i)
        tile[grp * 16 + i][lc] = src[(size_t)i * 2304];
    __syncthreads();
    short* dsth = vth + ((size_t)bh * 64 + grp * 16) * Sc + s0 + lc;
    short* dstl = vtl + ((size_t)bh * 64 + grp * 16) * Sc + s0 + lc;
#pragma unroll
    for (int i = 0; i < 16; ++i) {
        float v = tile[lc][grp * 16 + i];
        short hh = f2bf(v);
        dsth[(size_t)i * Sc] = hh;
        dstl[(size_t)i * Sc] = f2bf(v - bf2f(hh));
    }
}

// ---------------------------------------------------------------------------
// MFMA flash-attention partial. r13: single barrier per tile + double-
// buffered V stage. r12 PMC showed neither pipe saturated (MfmaUtil 22%,
// VALU 33%, ~22K cy/tile-phase vs ~9K pipe work): the 2-barrier serial
// chain {barrier, V-stage, QK, barrier, softmax, PV} was the cost. New
// order: QK(t) -> barrier -> stage V[t+1] into buf^1 (overlaps softmax/PV)
// -> softmax+PV(t) from buf. Race audit: V[t] writes (iter t-1, post-
// barrier) vs PV(t) reads separated by barrier(t); stage writes to buf^1
// vs PV(t-1) reads of same buffer separated by barrier(t). LDS 64KB ->
// 2 blocks/CU (explicit occupancy-vs-barrier test).
__global__ __launch_bounds__(256, 2) void attn_mfma_kernel(
    const float* __restrict__ qkv,
    const short* __restrict__ kph, const short* __restrict__ kpl,
    const short* __restrict__ vth, const short* __restrict__ vtl,
    float* __restrict__ po, float* __restrict__ pm, float* __restrict__ pl)
{
    __shared__ __attribute__((aligned(16))) short VhS[2][4096]; // V A-frags hi (dbuf)
    __shared__ __attribute__((aligned(16))) short VlS[2][4096]; // V A-frags lo (dbuf)
    __shared__ __attribute__((aligned(16))) short PhS[8192];    // per-wave P B-frags hi
    __shared__ __attribute__((aligned(16))) short PlS[8192];    // per-wave P B-frags lo

    const int tid = threadIdx.x, lane = tid & 63, wid = tid >> 6;
    const int quad = lane >> 4, l15 = lane & 15;
    const int bh = blockIdx.y;              // b*Hc + h
    const int b = bh / Hc, h = bh % Hc;
    const int chunk = blockIdx.z;
    const int qg = blockIdx.x * 128 + wid * 32;   // wave q base within S
    const int kvb = chunk * 512;
    const int wbase = wid * 2048;

    // Q B-frags (persist in regs): q = qg + nt*16 + l15, d = ks*32 + quad*8 + j
    bf16x8 qh[2][2], ql[2][2];
#pragma unroll
    for (int nt = 0; nt < 2; ++nt) {
        const float* qp = qkv + ((size_t)(b * Sc + qg + nt * 16 + l15)) * 2304
                        + h * 64 + quad * 8;
#pragma unroll
        for (int ks = 0; ks < 2; ++ks) {
            float4 f0 = *(const float4*)(qp + ks * 32);
            float4 f1 = *(const float4*)(qp + ks * 32 + 4);
            float v[8] = {f0.x * 0.125f, f0.y * 0.125f, f0.z * 0.125f, f0.w * 0.125f,
                          f1.x * 0.125f, f1.y * 0.125f, f1.z * 0.125f, f1.w * 0.125f};
            split8v(v, qh[nt][ks], ql[nt][ks]);
        }
    }

    f32x4 oacc[4][2];                       // O^T: [mtd (d)][nt (q)]
#pragma unroll
    for (int i = 0; i < 4; ++i)
#pragma unroll
        for (int j = 0; j < 2; ++j) oacc[i][j] = (f32x4){0.f, 0.f, 0.f, 0.f};
    float mrun[2] = {-1e30f, -1e30f}, lrun[2] = {0.f, 0.f};

    // helper: stage V tile tt into buffer bb (pure copy from V^T planes)
    auto stageV = [&](int tt, int bb) {
#pragma unroll
        for (int it = 0; it < 2; ++it) {
            int slot = tid + it * 256;      // 0..511: frag(ks*4+mtd) x lane
            int f = slot >> 6, ln = slot & 63;
            int sks = f >> 2, smtd = f & 3;
            int sl15 = ln & 15, squad = ln >> 4;
            size_t va = ((size_t)bh * 64 + smtd * 16 + sl15) * Sc
                      + kvb + tt * 64 + sks * 32 + squad * 8;
            *(bf16x8*)&VhS[bb][slot * 8] = *(const bf16x8*)&vth[va];
            *(bf16x8*)&VlS[bb][slot * 8] = *(const bf16x8*)&vtl[va];
        }
    };

    stageV(0, 0);                           // prologue

    for (int t = 0; t < 8; ++t) {
        const int cur = t & 1;
        const int kv0 = kvb + t * 64;
        // ---- QK^T: S^T[kv][q], K frags direct from pre-split planes
        f32x4 sacc[4][2];
#pragma unroll
        for (int i = 0; i < 4; ++i)
#pragma unroll
            for (int j = 0; j < 2; ++j) sacc[i][j] = (f32x4){0.f, 0.f, 0.f, 0.f};
#pragma unroll
        for (int ks = 0; ks < 2; ++ks) {
            bf16x8 kh[4], kl[4];
#pragma unroll
            for (int mt = 0; mt < 4; ++mt) {
                const size_t ka = (size_t)(b * Sc + kv0 + mt * 16 + l15) * 768
                                + h * 64 + ks * 32 + quad * 8;
                kh[mt] = *(const bf16x8*)&kph[ka];
                kl[mt] = *(const bf16x8*)&kpl[ka];
            }
#pragma unroll
            for (int mt = 0; mt < 4; ++mt)
#pragma unroll
                for (int nt = 0; nt < 2; ++nt) {
                    sacc[mt][nt] = __builtin_amdgcn_mfma_f32_16x16x32_bf16(kh[mt], qh[nt][ks], sacc[mt][nt], 0, 0, 0);
                    sacc[mt][nt] = __builtin_amdgcn_mfma_f32_16x16x32_bf16(kh[mt], ql[nt][ks], sacc[mt][nt], 0, 0, 0);
                    sacc[mt][nt] = __builtin_amdgcn_mfma_f32_16x16x32_bf16(kl[mt], qh[nt][ks], sacc[mt][nt], 0, 0, 0);
                }
        }
        __syncthreads();    // V[t] (written iter t-1 / prologue) visible;
                            // PV(t-1) reads of buf^1 complete
        // ---- stage V[t+1] into the other buffer (overlaps softmax+PV)
        if (t + 1 < 8) stageV(t + 1, cur ^ 1);
        // ---- online softmax (row = q; reduce over regs + quads)
#pragma unroll
        for (int nt = 0; nt < 2; ++nt) {
            float mx = -1e30f;
#pragma unroll
            for (int mt = 0; mt < 4; ++mt)
#pragma unroll
                for (int r = 0; r < 4; ++r) mx = fmaxf(mx, sacc[mt][nt][r]);
            mx = fmaxf(mx, __shfl_xor(mx, 16, 64));
            mx = fmaxf(mx, __shfl_xor(mx, 32, 64));
            float nm = fmaxf(mrun[nt], mx);
            float sf = __expf(mrun[nt] - nm);
            mrun[nt] = nm;
            float ladd = 0.f;
#pragma unroll
            for (int mt = 0; mt < 4; ++mt)
#pragma unroll
                for (int r = 0; r < 4; ++r) {
                    float p = __expf(sacc[mt][nt][r] - nm);
                    sacc[mt][nt][r] = p;
                    ladd += p;
                }
            ladd += __shfl_xor(ladd, 16, 64);
            ladd += __shfl_xor(ladd, 32, 64);
            lrun[nt] = lrun[nt] * sf + ladd;
#pragma unroll
            for (int mtd = 0; mtd < 4; ++mtd)
#pragma unroll
                for (int r = 0; r < 4; ++r) oacc[mtd][nt][r] *= sf;
        }
        // ---- P -> LDS (own wave region; B-frag order; short4 = 4 consec kv)
#pragma unroll
        for (int mt = 0; mt < 4; ++mt)
#pragma unroll
            for (int nt = 0; nt < 2; ++nt) {
                short4 ph, pw;
                float p0 = sacc[mt][nt][0], p1 = sacc[mt][nt][1];
                float p2 = sacc[mt][nt][2], p3 = sacc[mt][nt][3];
                ph.x = f2bf(p0); pw.x = f2bf(p0 - bf2f(ph.x));
                ph.y = f2bf(p1); pw.y = f2bf(p1 - bf2f(ph.y));
                ph.z = f2bf(p2); pw.z = f2bf(p2 - bf2f(ph.z));
                ph.w = f2bf(p3); pw.w = f2bf(p3 - bf2f(ph.w));
                int idx = wbase + ((mt >> 1) * 2 + nt) * 512
                        + (((mt & 1) * 2 + (quad >> 1)) * 16 + l15) * 8
                        + (quad & 1) * 4;
                *(short4*)&PhS[idx] = ph;
                *(short4*)&PlS[idx] = pw;
            }
        // ---- PV: O^T += V^T @ P^T (V from buf[cur]; P same-wave LDS)
#pragma unroll
        for (int ks = 0; ks < 2; ++ks) {
            bf16x8 vh[4], vl[4], pbh[2], pbl[2];
#pragma unroll
            for (int mtd = 0; mtd < 4; ++mtd) {
                int va = (ks * 4 + mtd) * 512 + lane * 8;
                vh[mtd] = *(const bf16x8*)&VhS[cur][va];
                vl[mtd] = *(const bf16x8*)&VlS[cur][va];
            }
#pragma unroll
            for (int nt = 0; nt < 2; ++nt) {
                int pa = wbase + (ks * 2 + nt) * 512 + lane * 8;
                pbh[nt] = *(const bf16x8*)&PhS[pa];
                pbl[nt] = *(const bf16x8*)&PlS[pa];
            }
#pragma unroll
            for (int mtd = 0; mtd < 4; ++mtd)
#pragma unroll
                for (int nt = 0; nt < 2; ++nt) {
                    oacc[mtd][nt] = __builtin_amdgcn_mfma_f32_16x16x32_bf16(vh[mtd], pbh[nt], oacc[mtd][nt], 0, 0, 0);
                    oacc[mtd][nt] = __builtin_amdgcn_mfma_f32_16x16x32_bf16(vh[mtd], pbl[nt], oacc[mtd][nt], 0, 0, 0);
                    oacc[mtd][nt] = __builtin_amdgcn_mfma_f32_16x16x32_bf16(vl[mtd], pbh[nt], oacc[mtd][nt], 0, 0, 0);
                }
        }
    }

    // ---- epilogue: O^T lane holds 4 consecutive d per (mtd,nt) -> float4
    const size_t qrow = (size_t)bh * Sc + qg;
#pragma unroll
    for (int nt = 0; nt < 2; ++nt) {
        float* pob = po + ((size_t)chunk * NQ + qrow + nt * 16 + l15) * 64;
#pragma unroll
        for (int mtd = 0; mtd < 4; ++mtd) {
            float4 o4;
            o4.x = oacc[mtd][nt][0]; o4.y = oacc[mtd][nt][1];
            o4.z = oacc[mtd][nt][2]; o4.w = oacc[mtd][nt][3];
            *(float4*)(pob + mtd * 16 + quad * 4) = o4;
        }
        if (quad == 0) {
            pm[(size_t)chunk * NQ + qrow + nt * 16 + l15] = mrun[nt];
            pl[(size_t)chunk * NQ + qrow + nt * 16 + l15] = lrun[nt];
        }
    }
}

__global__ __launch_bounds__(256) void attn_combine_kernel(
    const float* __restrict__ po, const float* __restrict__ pm,
    const float* __restrict__ pl, float* __restrict__ ao)
{
    const int tid = threadIdx.x;
    const int d = tid & 63;
    const int qi = blockIdx.x * 4 + (tid >> 6);
    const int bh = qi >> 11;
    const int s = qi & (Sc - 1);
    const int b = bh / Hc, h = bh % Hc;
    float m0 = pm[qi], m1 = pm[NQ + qi], m2 = pm[2*NQ + qi], m3 = pm[3*NQ + qi];
    float M = fmaxf(fmaxf(m0, m1), fmaxf(m2, m3));
    float w0 = __expf(m0 - M), w1 = __expf(m1 - M);
    float w2 = __expf(m2 - M), w3 = __expf(m3 - M);
    float l = w0 * pl[qi] + w1 * pl[NQ + qi] + w2 * pl[2*NQ + qi] + w3 * pl[3*NQ + qi];
    float o = w0 * po[(size_t)qi * 64 + d]
            + w1 * po[((size_t)NQ + qi) * 64 + d]
            + w2 * po[((size_t)2*NQ + qi) * 64 + d]
            + w3 * po[((size_t)3*NQ + qi) * 64 + d];
    ao[((size_t)(b * Sc + s)) * Dm + h * 64 + d] = o / l;
}

// ---------------------------------------------------------------------------
__global__ __launch_bounds__(256) void conv_silu_kernel(
    const float* __restrict__ xz, const float* __restrict__ cw,
    const float* __restrict__ cb, float* __restrict__ u)
{
    int id = blockIdx.x * 256 + threadIdx.x;
    int d = id % DI;
    int r = id / DI;
    int s = r & (Sc - 1);
    int b = r >> 11;
    float acc = cb[d];
#pragma unroll
    for (int j = 0; j < 4; ++j) {
        int sp = s + j - 3;
        if (sp >= 0)
            acc += xz[((size_t)(b * Sc + sp)) * (2 * DI) + d] * cw[d * 4 + j];
    }
    u[id] = acc / (1.f + __expf(-acc));
}

// ---------------------------------------------------------------------------
// Segmented parallel scan, coalesced (r5-verified). Block = (b, 16 dd).
__global__ __launch_bounds__(512) void scan_kernel(
    const float* __restrict__ delta, const float* __restrict__ u,
    const float* __restrict__ dbc, const float* __restrict__ A_log,
    const float* __restrict__ Dp, float* __restrict__ y)
{
    constexpr int GDD  = 16;
    constexpr int NSEG = 32;
    constexpr int LSEG = Sc / NSEG;        // 64
    const int tid = threadIdx.x;
    const int ddl = tid & 15;
    const int seg = tid >> 4;              // 0..31
    const int blk = blockIdx.x;            // 0..Bc*(DI/GDD)-1
    const int b = blk / (DI / GDD);
    const int dd0 = (blk % (DI / GDD)) * GDD;
    const int dd = dd0 + ddl;

    float Av[NST];
#pragma unroll
    for (int n = 0; n < NST; ++n) Av[n] = -__expf(A_log[dd * NST + n]);
    const float Dv = Dp[dd];

    const float* dbase = delta + (size_t)b * Sc * DI + dd;
    const float* ubase = u     + (size_t)b * Sc * DI + dd;
    const float* cbase = dbc   + (size_t)b * Sc * 80 + DTR;

    __shared__ float sdtS[NSEG][GDD];
    __shared__ float hendS[NSEG][GDD][NST];
    __shared__ float hstartS[NSEG][GDD][NST];

    const int t0 = seg * LSEG;
    float h[NST];
#pragma unroll
    for (int n = 0; n < NST; ++n) h[n] = 0.f;
    float sdt = 0.f;
#pragma unroll 2
    for (int i = 0; i < LSEG; ++i) {
        size_t t = t0 + i;
        float dt = dbase[t * DI];
        float du = dt * ubase[t * DI];
        sdt += dt;
        const float4* bp = (const float4*)(cbase + t * 80);
        float4 B0 = bp[0], B1 = bp[1], B2 = bp[2], B3 = bp[3];
        float Bv[NST] = {B0.x, B0.y, B0.z, B0.w, B1.x, B1.y, B1.z, B1.w,
                         B2.x, B2.y, B2.z, B2.w, B3.x, B3.y, B3.z, B3.w};
#pragma unroll
        for (int n = 0; n < NST; ++n)
            h[n] = __expf(dt * Av[n]) * h[n] + du * Bv[n];
    }
    sdtS[seg][ddl] = sdt;
#pragma unroll
    for (int n = 0; n < NST; ++n) hendS[seg][ddl][n] = h[n];
    __syncthreads();
    if (tid < GDD * NST) {
        const int cn = tid >> 4;
        const float Avn = Av[cn];
        float hs = 0.f;
#pragma unroll
        for (int s = 0; s < NSEG; ++s) {
            hstartS[s][ddl][cn] = hs;
            hs = __expf(Avn * sdtS[s][ddl]) * hs + hendS[s][ddl][cn];
        }
    }
    __syncthreads();
#pragma unroll
    for (int n = 0; n < NST; ++n) h[n] = hstartS[seg][ddl][n];
    float* yp = y + (size_t)b * Sc * DI + dd;
#pragma unroll 2
    for (int i = 0; i < LSEG; ++i) {
        size_t t = t0 + i;
        float dt = dbase[t * DI];
        float uu = ubase[t * DI];
        float du = dt * uu;
        const float4* bp = (const float4*)(cbase + t * 80);
        float4 B0 = bp[0], B1 = bp[1], B2 = bp[2], B3 = bp[3];
        float4 C0 = bp[4], C1 = bp[5], C2 = bp[6], C3 = bp[7];
        float Bv[NST] = {B0.x, B0.y, B0.z, B0.w, B1.x, B1.y, B1.z, B1.w,
                         B2.x, B2.y, B2.z, B2.w, B3.x, B3.y, B3.z, B3.w};
        float Cv[NST] = {C0.x, C0.y, C0.z, C0.w, C1.x, C1.y, C1.z, C1.w,
                         C2.x, C2.y, C2.z, C2.w, C3.x, C3.y, C3.z, C3.w};
        float p = 0.f;
#pragma unroll
        for (int n = 0; n < NST; ++n) {
            h[n] = __expf(dt * Av[n]) * h[n] + du * Bv[n];
            p += h[n] * Cv[n];
        }
        yp[t * DI] = p + uu * Dv;
    }
}

// ---------------------------------------------------------------------------
__global__ __launch_bounds__(256) void ssmin_kernel(
    float* __restrict__ y, const float* __restrict__ xz)
{
    int id = blockIdx.x * 256 + threadIdx.x;
    int d = id % DI;
    int r = id / DI;
    float z = xz[(size_t)r * (2 * DI) + DI + d];
    y[id] = y[id] * (z / (1.f + __expf(-z)));
}

// ---------------------------------------------------------------------------
__global__ __launch_bounds__(256) void x1_kernel(
    const float* __restrict__ x, const float* __restrict__ g,
    const float* __restrict__ at, const float* __restrict__ sm,
    float* __restrict__ x1)
{
    int id = blockIdx.x * 256 + threadIdx.x;
    float gv = g[id];
    x1[id] = x[id] + gv * at[id] + (1.f - gv) * sm[id];
}

// ---------------------------------------------------------------------------
__global__ __launch_bounds__(256) void rowdot_kernel(
    const float* __restrict__ rh, const float* __restrict__ w2,
    const float* __restrict__ b2, float* __restrict__ sc)
{
    int lane = threadIdx.x & 63;
    int t = blockIdx.x * 4 + (threadIdx.x >> 6);
    const float* rp = rh + (size_t)t * 192;
    float sum = rp[lane] * w2[lane] + rp[lane + 64] * w2[lane + 64]
              + rp[lane + 128] * w2[lane + 128];
#pragma unroll
    for (int off = 32; off; off >>= 1) sum += __shfl_down(sum, off, 64);
    if (lane == 0) sc[t] = sum + b2[0];
}

// ---------------------------------------------------------------------------
// Top-k via in-LDS bitonic sort (r4-verified).
__global__ __launch_bounds__(256) void topk_kernel(
    const float* __restrict__ sc, int* __restrict__ idxb)
{
    __shared__ unsigned long long keys[Sc];   // 16 KB
    const int b = blockIdx.x, tid = threadIdx.x;
    for (int i = tid; i < Sc; i += 256) {
        unsigned u = __float_as_uint(sc[(size_t)b * Sc + i]);
        unsigned ou = (u & 0x80000000u) ? ~u : (u | 0x80000000u);
        keys[i] = ((unsigned long long)ou << 32) | (unsigned)(Sc - 1 - i);
    }
    __syncthreads();
    for (int size = 2; size <= Sc; size <<= 1) {
        for (int stride = size >> 1; stride > 0; stride >>= 1) {
#pragma unroll 4
            for (int t = tid; t < Sc / 2; t += 256) {
                int lo = t & (stride - 1);
                int i = ((t ^ lo) << 1) | lo;
                int j = i | stride;
                bool asc = ((i & size) == 0);
                unsigned long long a = keys[i], c = keys[j];
                if (asc ? (a < c) : (a > c)) { keys[i] = c; keys[j] = a; }
            }
            __syncthreads();
        }
    }
    if (tid < CAP)
        idxb[b * CAP + tid] = Sc - 1 - (int)(keys[tid] & 0xFFFFFFFFu);
}

// ---------------------------------------------------------------------------
__global__ __launch_bounds__(256) void gather_kernel(
    const float* __restrict__ xn2, const int* __restrict__ idxb,
    float* __restrict__ Xsel)
{
    int i = blockIdx.x;
    int b = i >> 8;
    int t = idxb[i];
    const float* src = xn2 + ((size_t)(b * Sc + t)) * Dm;
    float* dst = Xsel + (size_t)i * Dm;
    int c = threadIdx.x;
    dst[c] = src[c]; dst[c + 256] = src[c + 256]; dst[c + 512] = src[c + 512];
}

__global__ __launch_bounds__(256) void finaladd_kernel(
    const float* __restrict__ x1, const float* __restrict__ xn2,
    float* __restrict__ out)
{
    int id = blockIdx.x * 256 + threadIdx.x;
    out[id] = x1[id] + xn2[id];
}

__global__ __launch_bounds__(256) void scatter_kernel(
    const float* __restrict__ x1, const float* __restrict__ proc,
    const int* __restrict__ idxb, float* __restrict__ out)
{
    int i = blockIdx.x;
    int b = i >> 8;
    int t = idxb[i];
    size_t ro = ((size_t)(b * Sc + t)) * Dm;
    const float* pp = proc + (size_t)i * Dm;
    int c = threadIdx.x;
    out[ro + c]       = x1[ro + c]       + pp[c];
    out[ro + c + 256] = x1[ro + c + 256] + pp[c + 256];
    out[ro + c + 512] = x1[ro + c + 512] + pp[c + 512];
}

// ---------------------------------------------------------------------------
extern "C" void kernel_launch(void* const* d_in, const int* in_sizes, int n_in,
                              void* d_out, int out_size, void* d_ws, size_t ws_size,
                              hipStream_t stream)
{
    (void)in_sizes; (void)n_in; (void)out_size; (void)ws_size;
    const float* x          = (const float*)d_in[0];
    const float* ln1_w      = (const float*)d_in[1];
    const float* ln1_b      = (const float*)d_in[2];
    const float* ln2_w      = (const float*)d_in[3];
    const float* ln2_b      = (const float*)d_in[4];
    const float* qkv_w      = (const float*)d_in[5];
    const float* attn_out_w = (const float*)d_in[6];
    const float* attn_out_b = (const float*)d_in[7];
    const float* in_proj_w  = (const float*)d_in[8];
    const float* conv_w     = (const float*)d_in[9];
    const float* conv_b     = (const float*)d_in[10];
    const float* x_proj_w   = (const float*)d_in[11];
    const float* dt_w       = (const float*)d_in[12];
    const float* dt_b       = (const float*)d_in[13];
    const float* A_log      = (const float*)d_in[14];
    const float* Dvec       = (const float*)d_in[15];
    const float* ssm_out_w  = (const float*)d_in[16];
    const float* gate_w     = (const float*)d_in[17];
    const float* gate_b     = (const float*)d_in[18];
    const float* ffn_w1     = (const float*)d_in[19];
    const float* ffn_b1     = (const float*)d_in[20];
    const float* ffn_w2     = (const float*)d_in[21];
    const float* ffn_b2     = (const float*)d_in[22];
    const float* r_w1       = (const float*)d_in[23];
    const float* r_b1       = (const float*)d_in[24];
    const float* r_w2       = (const float*)d_in[25];
    const float* r_b2       = (const float*)d_in[26];
    float* out = (float*)d_out;

    // ---- Layout (floats). End = 53,318,144 floats = 213.27 MB (< 215.24 proven).
    float* ws  = (float*)d_ws;
    float* xn  = ws;                       // TOK           (live 1-6)
    float* ao  = ws + TOK;                 // TOK           (live 4.5-5)
    float* y   = ws;                       // 2*TOK         (live 10-12; xn/ao dead)
    float* qkv = ws + 2 * TOK;             // 9.44M         (live 2-4)
    float* xz  = ws + 2 * TOK;             // 12.58M        (live 6-11; over qkv)
    float* u   = ws + 18874368;            // 6.29M         (live 7-10)
    float* xn2 = ws + 18874368;            // TOK           (live 16+; u dead)
    // pre-split attention planes live 3.5-4, in u's region (u dead until 7):
    short* kph = (short*)(ws + 18874368);  // K hi  [M_,768] = 3.146M shorts
    short* kpl = (short*)(ws + 20447232);  // K lo
    short* vth = (short*)(ws + 22020096);  // V^T hi [bh,64,Sc]
    short* vtl = (short*)(ws + 23592960);  // V^T lo; ends 25165824
    // split-K partials (steps 21-22): fp1 in dead y region, fp2 in dead xz
    float* fp1 = ws;                       // 4 x 1,572,864 = 2*TOK (y dead)
    float* fp2 = ws + 2 * TOK;             // 8 x 393,216 = TOK (xz dead)
    float* dbc = ws + 25165824;            // 327,680       (live 8-10)
    float* attn_out = ws + 25493504;       // TOK           (live 5-15)
    float* ssm_out  = ws + 28639232;       // TOK           (live 12-15)
    float* g        = ws + 31784960;       // TOK           (live 13-15)
    float* x1       = ws + 34930688;       // TOK           (live 15+)
    float* po    = attn_out;               // 12.58M        (live 4-4.5; spans 4 slots)
    float* delta = ssm_out;                // 6.29M         (live 9-10; ssm_out+g slots)
    float* rh  = ws + 38076416;            // 786,432       (live 17-18)
    float* pmb = rh + 64;                  // 196,608 (guard gap vs po end)
    float* plb = pmb + (size_t)NCH * NQ;   // 196,608
    float* sc  = ws + 38862848;            // 4,096  -> ends 38,866,944
    int*   idxb = (int*)(ws + 38866944);   // 512 ints = 512 float slots
    float* Xsel = ws + 38867456;           // 393,216 -> ends 39,260,672
    float* Hsel = ws + 39260672;           // 1,572,864 -> ends 40,833,536
    float* proc = ws + 40833536;           // 393,216 -> ends 41,226,752
    short* wb   = (short*)(ws + 41226752); // 24,182,784 shorts (12,091,392 floats)
    short* qkvh = wb,            *qkvl = wb + 1769472;
    short* atth = wb + 3538944,  *attl = wb + 4128768;
    short* inph = wb + 4718592,  *inpl = wb + 7077888;
    short* xpjh = wb + 9437184,  *xpjl = wb + 9633792;
    short* ssmh = wb + 10027008, *ssml = wb + 11206656;
    short* g1h  = wb + 12386304, *g1l  = wb + 12976128;
    short* g2h  = wb + 13565952, *g2l  = wb + 14155776;
    short* f1h  = wb + 14745600, *f1l  = wb + 17104896;
    short* f2h  = wb + 19464192, *f2l  = wb + 21823488;

    // ---- weight pre-swizzles (every launch)
    auto WS = [&](const float* W, short* Wh, short* Wl, int K, int N, int Kp, int Np) {
        int total = Kp * Np;
        wswz_kernel<<<(total + 255) / 256, 256, 0, stream>>>(W, Wh, Wl, K, N, Kp, Np);
    };
    WS(qkv_w, qkvh, qkvl, 768, 2304, 768, 2304);
    WS(attn_out_w, atth, attl, 768, 768, 768, 768);
    WS(in_proj_w, inph, inpl, 768, 3072, 768, 3072);
    WS(x_proj_w, xpjh, xpjl, 1536, 80, 1536, 128);
    WS(ssm_out_w, ssmh, ssml, 1536, 768, 1536, 768);
    WS(gate_w, g1h, g1l, 768, 768, 768, 768);
    WS(gate_w + (size_t)768 * 768, g2h, g2l, 768, 768, 768, 768);
    WS(ffn_w1, f1h, f1l, 768, 3072, 768, 3072);
    WS(ffn_w2, f2h, f2l, 3072, 768, 3072, 768);

    // 1. LN1
    ln_kernel<<<M_, 256, 0, stream>>>(x, ln1_w, ln1_b, xn);
    // 2. QKV
    gemm_bf3<0><<<dim3(18, 32), 256, 0, stream>>>(xn, Dm, qkvh, qkvl, 144,
        nullptr, qkv, M_, 2304, 768, 0, 0);
    // 3. RoPE
    rope_kernel<<<(Bc * Sc * Hc * 32) / 256, 256, 0, stream>>>(qkv);
    // 3.5 pre-split K (post-RoPE) + transpose+split V
    ksplit_kernel<<<(M_ * 96) / 256, 256, 0, stream>>>(qkv, kph, kpl);
    vtrans_kernel<<<Bc * Hc * (Sc / 64), 256, 0, stream>>>(qkv, vth, vtl);
    // 4. attention (MFMA flash partial + combine)
    attn_mfma_kernel<<<dim3(Sc / 128, Bc * Hc, NCH), 256, 0, stream>>>(
        qkv, kph, kpl, vth, vtl, po, pmb, plb);
    attn_combine_kernel<<<NQ / 4, 256, 0, stream>>>(po, pmb, plb, ao);
    // 5. attn_out projection (po dead)
    gemm_bf3<1><<<dim3(6, 32), 256, 0, stream>>>(ao, Dm, atth, attl, 48,
        attn_out_b, attn_out, M_, 768, 768, 0, 0);
    // 6. in_proj (qkv dead; xz overwrites it)
    gemm_bf3<2><<<dim3(24, 32), 256, 0, stream>>>(xn, Dm, inph, inpl, 192,
        nullptr, xz, M_, 3072, 768, 0, 0);
    // 7. conv + SiLU (kph..vtl dead -> u)
    conv_silu_kernel<<<(M_ * DI) / 256, 256, 0, stream>>>(xz, conv_w, conv_b, u);
    // 8. x_proj (N=80, Npad=128)
    gemm_bf3<3><<<dim3(1, 32), 256, 0, stream>>>(u, DI, xpjh, xpjl, 8,
        nullptr, dbc, M_, 80, 1536, 0, 0);
    // 9. delta = softplus(dbc[:,:48] @ dt_w + dt_b), dedicated fp32 kernel
    delta_kernel<<<M_, 256, 0, stream>>>(dbc, dt_w, dt_b, delta);
    // 10. scan -> y (xn/ao dead); coalesced segmented scan, block = (b, 16 dd)
    scan_kernel<<<Bc * (DI / 16), 512, 0, stream>>>(delta, u, dbc, A_log, Dvec, y);
    // 11. y *= silu(z) in place (delta dead after scan)
    ssmin_kernel<<<(M_ * DI) / 256, 256, 0, stream>>>(y, xz);
    // 12. ssm_out
    gemm_bf3<5><<<dim3(6, 32), 256, 0, stream>>>(y, DI, ssmh, ssml, 48,
        nullptr, ssm_out, M_, 768, 1536, 0, 0);
    // 13/14. gate
    gemm_bf3<6><<<dim3(6, 32), 256, 0, stream>>>(attn_out, Dm, g1h, g1l, 48,
        nullptr, g, M_, 768, 768, 0, 0);
    gemm_bf3<7><<<dim3(6, 32), 256, 0, stream>>>(ssm_out, Dm, g2h, g2l, 48,
        gate_b, g, M_, 768, 768, 2, 1);
    // 15. x1
    x1_kernel<<<(M_ * Dm) / 256, 256, 0, stream>>>(x, g, attn_out, ssm_out, x1);
    // 16. LN2 (u dead -> xn2)
    ln_kernel<<<M_, 256, 0, stream>>>(x1, ln2_w, ln2_b, xn2);
    // 17. router (pure fp32, selection-critical; 64x64 tiles, grid 3x64)
    gemm_kernel<8><<<dim3(3, 64), 256, 0, stream>>>(xn2, Dm, r_w1, r_b1, rh, M_, 192, 768, 3, 0);
    // 18. scores
    rowdot_kernel<<<M_ / 4, 256, 0, stream>>>(rh, r_w2, r_b2, sc);
    // 19. top-k (bitonic)
    topk_kernel<<<Bc, 256, 0, stream>>>(sc, idxb);
    // 20. gather
    gather_kernel<<<Bc * CAP, 256, 0, stream>>>(xn2, idxb, Xsel);
    // 21. FFN1 split-K x4 (partials in dead y region)
    gemm_bf3_pk<9><<<dim3(24, 4, 4), 256, 0, stream>>>(Xsel, Dm, f1h, f1l, 192,
        fp1, Bc * CAP, DF, 192);
    pkreduce_kernel<<<(Bc * CAP * DF) / 256, 256, 0, stream>>>(
        fp1, 4, Bc * CAP * DF, DF, ffn_b1, Hsel, 4);
    // 22. FFN2 split-K x8 (partials in dead xz region)
    gemm_bf3_pk<10><<<dim3(6, 4, 8), 256, 0, stream>>>(Hsel, DF, f2h, f2l, 48,
        fp2, Bc * CAP, 768, 384);
    pkreduce_kernel<<<(Bc * CAP * 768) / 256, 256, 0, stream>>>(
        fp2, 8, Bc * CAP * 768, 768, ffn_b2, proc, 0);
    // 23. out = x1 + xn2
    finaladd_kernel<<<(M_ * Dm) / 256, 256, 0, stream>>>(x1, xn2, out);
    // 24. scatter
    scatter_kernel<<<Bc * CAP, 256, 0, stream>>>(x1, proc, idxb, out);
}

// Round 14
// 1273.959 us; speedup vs baseline: 1.0646x; 1.0646x over previous
//
#include <hip/hip_runtime.h>
#include <cstdint>
#include <cstddef>

// Problem constants
constexpr int Bc   = 2;
constexpr int Sc   = 2048;
constexpr int Dm   = 768;
constexpr int Hc   = 12;
constexpr int DI   = 1536;
constexpr int NST  = 16;
constexpr int DTR  = 48;
constexpr int CAP  = 256;
constexpr int DF   = 3072;
constexpr int M_   = Bc * Sc;        // 4096
constexpr int NQ   = Bc * Hc * Sc;   // 49152
constexpr int NCH  = 4;
constexpr size_t TOK = (size_t)M_ * Dm;   // 3,145,728

typedef __attribute__((ext_vector_type(8))) short bf16x8;
typedef __attribute__((ext_vector_type(4))) float f32x4;

__device__ __forceinline__ float apply_act(float v, int act) {
    switch (act) {
        case 1: return (v > 20.f) ? v : log1pf(__expf(v));
        case 2: return 1.f / (1.f + __expf(-v));
        case 3: return fmaxf(v, 0.f);
        case 4: return 0.5f * v * (1.f + erff(v * 0.70710678118654752f));
        default: return v;
    }
}
__device__ __forceinline__ short f2bf(float x) {   // RNE
    unsigned u = __float_as_uint(x);
    unsigned r = u + 0x7FFFu + ((u >> 16) & 1u);
    return (short)(r >> 16);
}
__device__ __forceinline__ float bf2f(short h) {
    return __uint_as_float(((unsigned)(unsigned short)h) << 16);
}
__device__ __forceinline__ void split8v(const float* v, bf16x8& hi, bf16x8& lo) {
#pragma unroll
    for (int j = 0; j < 8; ++j) {
        short hs = f2bf(v[j]);
        hi[j] = hs;
        lo[j] = f2bf(v[j] - bf2f(hs));
    }
}

// ---------------------------------------------------------------------------
// Weight pre-swizzle: fp32 [K x N] -> bf16 hi/lo in MFMA B-fragment order.
__global__ __launch_bounds__(256) void wswz_kernel(
    const float* __restrict__ W, short* __restrict__ Wh, short* __restrict__ Wl,
    int K, int N, int Kpad, int Npad)
{
    int id = blockIdx.x * 256 + threadIdx.x;
    if (id >= Kpad * Npad) return;
    int n = id % Npad, k = id / Npad;
    float v = (k < K && n < N) ? W[(size_t)k * N + n] : 0.f;
    short h = f2bf(v);
    short l = f2bf(v - bf2f(h));
    int NT = Npad >> 4;
    size_t off = ((((size_t)(k >> 5) * NT + (n >> 4)) * 4 + ((k >> 3) & 3)) * 16
                  + (n & 15)) * 8 + (k & 7);
    Wh[off] = h; Wl[off] = l;
}

// ---------------------------------------------------------------------------
// bf16x3 MFMA GEMM: fp32 A (row-major, lda), pre-swizzled bf16 B hi/lo.
// C = act(acc*C + A@W + bias). Tile 128x128x32, 4 waves of 64x64.
template <int ID>
__global__ __launch_bounds__(256, 2) void gemm_bf3(
    const float* __restrict__ A, int lda,
    const short* __restrict__ Bh, const short* __restrict__ Bl, int ntiles,
    const float* __restrict__ bias,
    float* __restrict__ C,
    int M, int N, int K, int act, int accflag)
{
    __shared__ __attribute__((aligned(16))) short AhS[4096];
    __shared__ __attribute__((aligned(16))) short AlS[4096];
    const int tid = threadIdx.x, lane = tid & 63, wid = tid >> 6;
    const int wm = wid >> 1, wn = wid & 1;
    const int bm = blockIdx.y * 128, bn = blockIdx.x * 128;

    f32x4 acc[4][4];
#pragma unroll
    for (int i = 0; i < 4; ++i)
#pragma unroll
        for (int j = 0; j < 4; ++j) acc[i][j] = (f32x4){0.f, 0.f, 0.f, 0.f};

    const int ksteps = (K + 31) >> 5;
    for (int ks = 0; ks < ksteps; ++ks) {
        const int k0 = ks << 5;
        bf16x8 bh[4], bl[4];
        const size_t bbase = ((size_t)ks * ntiles + (bn >> 4) + wn * 4) * 512
                           + (size_t)lane * 8;
#pragma unroll
        for (int t = 0; t < 4; ++t) {
            bh[t] = *(const bf16x8*)&Bh[bbase + (size_t)t * 512];
            bl[t] = *(const bf16x8*)&Bl[bbase + (size_t)t * 512];
        }
#pragma unroll
        for (int i = 0; i < 2; ++i) {
            int c = i * 256 + tid;          // chunk 0..511
            int l = c & 63;
            int m = ((c >> 6) << 4) + (l & 15);
            int q = l >> 4;
            int kk = k0 + q * 8;
            short4 h0, l0, h1, l1;
            if (kk + 8 <= K) {
                const float* ap = A + (size_t)(bm + m) * lda + kk;
                float4 f0 = *(const float4*)ap;
                float4 f1 = *(const float4*)(ap + 4);
                h0.x = f2bf(f0.x); l0.x = f2bf(f0.x - bf2f(h0.x));
                h0.y = f2bf(f0.y); l0.y = f2bf(f0.y - bf2f(h0.y));
                h0.z = f2bf(f0.z); l0.z = f2bf(f0.z - bf2f(h0.z));
                h0.w = f2bf(f0.w); l0.w = f2bf(f0.w - bf2f(h0.w));
                h1.x = f2bf(f1.x); l1.x = f2bf(f1.x - bf2f(h1.x));
                h1.y = f2bf(f1.y); l1.y = f2bf(f1.y - bf2f(h1.y));
                h1.z = f2bf(f1.z); l1.z = f2bf(f1.z - bf2f(h1.z));
                h1.w = f2bf(f1.w); l1.w = f2bf(f1.w - bf2f(h1.w));
            } else {
                h0 = short4{0,0,0,0}; l0 = h0; h1 = h0; l1 = h0;
            }
            int off = c * 8;
            *(short4*)&AhS[off]     = h0;
            *(short4*)&AhS[off + 4] = h1;
            *(short4*)&AlS[off]     = l0;
            *(short4*)&AlS[off + 4] = l1;
        }
        __syncthreads();
        bf16x8 ah[4], al[4];
#pragma unroll
        for (int t = 0; t < 4; ++t) {
            int ai = ((wm * 4 + t) * 64 + lane) * 8;
            ah[t] = *(const bf16x8*)&AhS[ai];
            al[t] = *(const bf16x8*)&AlS[ai];
        }
#pragma unroll
        for (int im = 0; im < 4; ++im)
#pragma unroll
            for (int in = 0; in < 4; ++in) {
                acc[im][in] = __builtin_amdgcn_mfma_f32_16x16x32_bf16(ah[im], bh[in], acc[im][in], 0, 0, 0);
                acc[im][in] = __builtin_amdgcn_mfma_f32_16x16x32_bf16(ah[im], bl[in], acc[im][in], 0, 0, 0);
                acc[im][in] = __builtin_amdgcn_mfma_f32_16x16x32_bf16(al[im], bh[in], acc[im][in], 0, 0, 0);
            }
        __syncthreads();
    }

    const int qrow = (lane >> 4) * 4;
#pragma unroll
    for (int im = 0; im < 4; ++im) {
        int rowb = bm + wm * 64 + im * 16 + qrow;
#pragma unroll
        for (int in = 0; in < 4; ++in) {
            int col = bn + wn * 64 + in * 16 + (lane & 15);
            if (col < N) {
#pragma unroll
                for (int r = 0; r < 4; ++r) {
                    size_t cidx = (size_t)(rowb + r) * N + col;
                    float v = acc[im][in][r];
                    if (accflag) v += C[cidx];
                    if (bias) v += bias[col];
                    C[cidx] = apply_act(v, act);
                }
            }
        }
    }
}

// ---------------------------------------------------------------------------
// Split-K variant (r9-verified): blockIdx.z selects a K-partition.
// r14: col<N guard on partial stores (enables N=80 x_proj with 128-wide tile).
template <int ID>
__global__ __launch_bounds__(256, 2) void gemm_bf3_pk(
    const float* __restrict__ A, int lda,
    const short* __restrict__ Bh, const short* __restrict__ Bl, int ntiles,
    float* __restrict__ Cpart,
    int M, int N, int Kpart)
{
    __shared__ __attribute__((aligned(16))) short AhS[4096];
    __shared__ __attribute__((aligned(16))) short AlS[4096];
    const int tid = threadIdx.x, lane = tid & 63, wid = tid >> 6;
    const int wm = wid >> 1, wn = wid & 1;
    const int bm = blockIdx.y * 128, bn = blockIdx.x * 128;
    const int kofs = blockIdx.z * Kpart;          // element offset into K
    const int kz0  = kofs >> 5;                   // global k-step base

    f32x4 acc[4][4];
#pragma unroll
    for (int i = 0; i < 4; ++i)
#pragma unroll
        for (int j = 0; j < 4; ++j) acc[i][j] = (f32x4){0.f, 0.f, 0.f, 0.f};

    const int ksteps = Kpart >> 5;
    for (int ks = 0; ks < ksteps; ++ks) {
        const int k0 = ks << 5;
        bf16x8 bh[4], bl[4];
        const size_t bbase = ((size_t)(kz0 + ks) * ntiles + (bn >> 4) + wn * 4) * 512
                           + (size_t)lane * 8;
#pragma unroll
        for (int t = 0; t < 4; ++t) {
            bh[t] = *(const bf16x8*)&Bh[bbase + (size_t)t * 512];
            bl[t] = *(const bf16x8*)&Bl[bbase + (size_t)t * 512];
        }
#pragma unroll
        for (int i = 0; i < 2; ++i) {
            int c = i * 256 + tid;          // chunk 0..511
            int l = c & 63;
            int m = ((c >> 6) << 4) + (l & 15);
            int q = l >> 4;
            int kk = kofs + k0 + q * 8;     // always in-range (K = parts*Kpart)
            const float* ap = A + (size_t)(bm + m) * lda + kk;
            float4 f0 = *(const float4*)ap;
            float4 f1 = *(const float4*)(ap + 4);
            short4 h0, l0, h1, l1;
            h0.x = f2bf(f0.x); l0.x = f2bf(f0.x - bf2f(h0.x));
            h0.y = f2bf(f0.y); l0.y = f2bf(f0.y - bf2f(h0.y));
            h0.z = f2bf(f0.z); l0.z = f2bf(f0.z - bf2f(h0.z));
            h0.w = f2bf(f0.w); l0.w = f2bf(f0.w - bf2f(h0.w));
            h1.x = f2bf(f1.x); l1.x = f2bf(f1.x - bf2f(h1.x));
            h1.y = f2bf(f1.y); l1.y = f2bf(f1.y - bf2f(h1.y));
            h1.z = f2bf(f1.z); l1.z = f2bf(f1.z - bf2f(h1.z));
            h1.w = f2bf(f1.w); l1.w = f2bf(f1.w - bf2f(h1.w));
            int off = c * 8;
            *(short4*)&AhS[off]     = h0;
            *(short4*)&AhS[off + 4] = h1;
            *(short4*)&AlS[off]     = l0;
            *(short4*)&AlS[off + 4] = l1;
        }
        __syncthreads();
        bf16x8 ah[4], al[4];
#pragma unroll
        for (int t = 0; t < 4; ++t) {
            int ai = ((wm * 4 + t) * 64 + lane) * 8;
            ah[t] = *(const bf16x8*)&AhS[ai];
            al[t] = *(const bf16x8*)&AlS[ai];
        }
#pragma unroll
        for (int im = 0; im < 4; ++im)
#pragma unroll
            for (int in = 0; in < 4; ++in) {
                acc[im][in] = __builtin_amdgcn_mfma_f32_16x16x32_bf16(ah[im], bh[in], acc[im][in], 0, 0, 0);
                acc[im][in] = __builtin_amdgcn_mfma_f32_16x16x32_bf16(ah[im], bl[in], acc[im][in], 0, 0, 0);
                acc[im][in] = __builtin_amdgcn_mfma_f32_16x16x32_bf16(al[im], bh[in], acc[im][in], 0, 0, 0);
            }
        __syncthreads();
    }

    float* Cp = Cpart + (size_t)blockIdx.z * M * N;
    const int qrow = (lane >> 4) * 4;
#pragma unroll
    for (int im = 0; im < 4; ++im) {
        int rowb = bm + wm * 64 + im * 16 + qrow;
#pragma unroll
        for (int in = 0; in < 4; ++in) {
            int col = bn + wn * 64 + in * 16 + (lane & 15);
            if (col < N) {
#pragma unroll
                for (int r = 0; r < 4; ++r)
                    Cp[(size_t)(rowb + r) * N + col] = acc[im][in][r];
            }
        }
    }
}

// Combine split-K partials: C = act(sum_p parts[p] + bias?).
__global__ __launch_bounds__(256) void pkreduce_kernel(
    const float* __restrict__ parts, int nparts, int MN, int N,
    const float* __restrict__ bias, float* __restrict__ C, int act)
{
    int id = blockIdx.x * 256 + threadIdx.x;
    if (id >= MN) return;
    float s = 0.f;
    for (int p = 0; p < nparts; ++p) s += parts[(size_t)p * MN + id];
    if (bias) s += bias[id % N];
    C[id] = apply_act(s, act);
}

// ---------------------------------------------------------------------------
// fp32 scalar GEMM (router projection only — selection-critical).
// 64x64 tiles (r10); per-output sequential-k fmaf order unchanged.
template <int ID>
__global__ __launch_bounds__(256, 2) void gemm_kernel(
    const float* __restrict__ A, int lda,
    const float* __restrict__ W,
    const float* __restrict__ bias,
    float* __restrict__ C,
    int M, int N, int K, int act, int accflag)
{
    __shared__ float As[16][68];
    __shared__ float Bs[16][68];
    const int tid = threadIdx.x;
    const int bm = blockIdx.y * 64;
    const int bn = blockIdx.x * 64;
    const int tx = tid & 15, ty = tid >> 4;
    float acc[4][4];
#pragma unroll
    for (int i = 0; i < 4; ++i)
#pragma unroll
        for (int j = 0; j < 4; ++j) acc[i][j] = 0.f;
    for (int k0 = 0; k0 < K; k0 += 16) {
        {
            int row = tid >> 2;            // 0..63
            int kc = (tid & 3) * 4;
            const float* ap = A + (size_t)(bm + row) * lda + (k0 + kc);
            float4 v = *(const float4*)ap;
            As[kc + 0][row] = v.x; As[kc + 1][row] = v.y;
            As[kc + 2][row] = v.z; As[kc + 3][row] = v.w;
        }
        {
            int row = tid >> 4;            // 0..15 (k)
            int col = (tid & 15) * 4;
            int gn = bn + col;
            const float* wp = W + (size_t)(k0 + row) * N + gn;
            float4 v;
            if (gn + 3 < N) v = *(const float4*)wp;
            else {
                v.x = (gn + 0 < N) ? wp[0] : 0.f;
                v.y = (gn + 1 < N) ? wp[1] : 0.f;
                v.z = (gn + 2 < N) ? wp[2] : 0.f;
                v.w = (gn + 3 < N) ? wp[3] : 0.f;
            }
            *(float4*)&Bs[row][col] = v;
        }
        __syncthreads();
#pragma unroll
        for (int kk = 0; kk < 16; ++kk) {
            float a[4], b[4];
            *(float4*)&a[0] = *(const float4*)&As[kk][ty * 4];
            *(float4*)&b[0] = *(const float4*)&Bs[kk][tx * 4];
#pragma unroll
            for (int i = 0; i < 4; ++i)
#pragma unroll
                for (int j = 0; j < 4; ++j)
                    acc[i][j] = fmaf(a[i], b[j], acc[i][j]);
        }
        __syncthreads();
    }
#pragma unroll
    for (int ii = 0; ii < 4; ++ii) {
        int row = bm + ty * 4 + ii;
#pragma unroll
        for (int jj = 0; jj < 4; ++jj) {
            int col = bn + tx * 4 + jj;
            if (col < N) {
                size_t cidx = (size_t)row * N + col;
                float v = acc[ii][jj];
                if (accflag) v += C[cidx];
                if (bias) v += bias[col];
                C[cidx] = apply_act(v, act);
            }
        }
    }
}

// ---------------------------------------------------------------------------
// delta = softplus(dbc[:, :48] @ dt_w + dt_b), fp32 (r11-verified).
__global__ __launch_bounds__(256) void delta_kernel(
    const float* __restrict__ dbc, const float* __restrict__ dt_w,
    const float* __restrict__ dt_b, float* __restrict__ delta)
{
    __shared__ float dlow[48];
    const int m = blockIdx.x;
    const int tid = threadIdx.x;
    if (tid < 48) dlow[tid] = dbc[(size_t)m * 80 + tid];
    __syncthreads();
    float acc[6];
#pragma unroll
    for (int i = 0; i < 6; ++i) acc[i] = 0.f;
    for (int k = 0; k < 48; ++k) {
        float a = dlow[k];
        const float* wr = dt_w + (size_t)k * DI;
#pragma unroll
        for (int i = 0; i < 6; ++i)
            acc[i] = fmaf(a, wr[tid + i * 256], acc[i]);
    }
    float* dp = delta + (size_t)m * DI;
#pragma unroll
    for (int i = 0; i < 6; ++i) {
        int n = tid + i * 256;
        float v = acc[i] + dt_b[n];
        dp[n] = (v > 20.f) ? v : log1pf(__expf(v));
    }
}

// ---------------------------------------------------------------------------
__global__ __launch_bounds__(256) void ln_kernel(
    const float* __restrict__ x, const float* __restrict__ w,
    const float* __restrict__ b, float* __restrict__ out)
{
    const int row = blockIdx.x, tid = threadIdx.x;
    const float* xp = x + (size_t)row * Dm;
    float v0 = xp[tid], v1 = xp[tid + 256], v2 = xp[tid + 512];
    float s1 = v0 + v1 + v2;
    float s2 = v0 * v0 + v1 * v1 + v2 * v2;
#pragma unroll
    for (int off = 32; off; off >>= 1) {
        s1 += __shfl_down(s1, off, 64);
        s2 += __shfl_down(s2, off, 64);
    }
    __shared__ float r1[4], r2[4];
    int wid = tid >> 6, lane = tid & 63;
    if (lane == 0) { r1[wid] = s1; r2[wid] = s2; }
    __syncthreads();
    s1 = r1[0] + r1[1] + r1[2] + r1[3];
    s2 = r2[0] + r2[1] + r2[2] + r2[3];
    float mu = s1 * (1.f / 768.f);
    float var = s2 * (1.f / 768.f) - mu * mu;
    float rstd = rsqrtf(var + 1e-5f);
    float* op = out + (size_t)row * Dm;
    op[tid]       = (v0 - mu) * rstd * w[tid]       + b[tid];
    op[tid + 256] = (v1 - mu) * rstd * w[tid + 256] + b[tid + 256];
    op[tid + 512] = (v2 - mu) * rstd * w[tid + 512] + b[tid + 512];
}

// ---------------------------------------------------------------------------
__global__ __launch_bounds__(256) void rope_kernel(float* __restrict__ qkv)
{
    int id = blockIdx.x * 256 + threadIdx.x;
    int i = id & 31;
    int h = (id >> 5) % Hc;
    int r = id / (32 * Hc);
    int s = r & (Sc - 1);
    float inv = powf(10000.f, -(float)(2 * i) * (1.f / 64.f));
    float f = (float)s * inv;
    float sn, cs;
    sincosf(f, &sn, &cs);
    float* base = qkv + (size_t)r * 2304 + h * 64 + i;
    float q1 = base[0], q2 = base[32];
    base[0]  = q1 * cs - q2 * sn;
    base[32] = q1 * sn + q2 * cs;
    float* kb = base + Dm;
    float k1 = kb[0], k2 = kb[32];
    kb[0]  = k1 * cs - k2 * sn;
    kb[32] = k1 * sn + k2 * cs;
}

// ---------------------------------------------------------------------------
// K split: post-RoPE K section of qkv -> bf16 hi/lo planes [M_, 768].
__global__ __launch_bounds__(256) void ksplit_kernel(
    const float* __restrict__ qkv, short* __restrict__ kph, short* __restrict__ kpl)
{
    int id = blockIdx.x * 256 + threadIdx.x;   // M_*96 total
    int r = id / 96;
    int c = (id - r * 96) * 8;
    const float* src = qkv + (size_t)r * 2304 + Dm + c;
    float4 f0 = *(const float4*)src;
    float4 f1 = *(const float4*)(src + 4);
    short4 h0, l0, h1, l1;
    h0.x = f2bf(f0.x); l0.x = f2bf(f0.x - bf2f(h0.x));
    h0.y = f2bf(f0.y); l0.y = f2bf(f0.y - bf2f(h0.y));
    h0.z = f2bf(f0.z); l0.z = f2bf(f0.z - bf2f(h0.z));
    h0.w = f2bf(f0.w); l0.w = f2bf(f0.w - bf2f(h0.w));
    h1.x = f2bf(f1.x); l1.x = f2bf(f1.x - bf2f(h1.x));
    h1.y = f2bf(f1.y); l1.y = f2bf(f1.y - bf2f(h1.y));
    h1.z = f2bf(f1.z); l1.z = f2bf(f1.z - bf2f(h1.z));
    h1.w = f2bf(f1.w); l1.w = f2bf(f1.w - bf2f(h1.w));
    short* dh = kph + (size_t)r * 768 + c;
    short* dl = kpl + (size_t)r * 768 + c;
    *(short4*)dh = h0; *(short4*)(dh + 4) = h1;
    *(short4*)dl = l0; *(short4*)(dl + 4) = l1;
}

// ---------------------------------------------------------------------------
// V transpose+split: qkv V section -> V^T bf16 hi/lo planes [bh, d(64), Sc].
// LDS 64x65 tile transpose (r6/r7-verified correct).
__global__ __launch_bounds__(256) void vtrans_kernel(
    const float* __restrict__ qkv, short* __restrict__ vth, short* __restrict__ vtl)
{
    __shared__ float tile[64][65];
    const int blk = blockIdx.x;              // Bc*Hc*32
    const int bh = blk >> 5;
    const int st = blk & 31;
    const int b = bh / Hc, h = bh % Hc;
    const int s0 = st * 64;
    const int tid = threadIdx.x;
    const int lc = tid & 63;                 // lane within 64
    const int grp = tid >> 6;                // 0..3
    const float* src = qkv + ((size_t)(b * Sc + s0 + grp * 16)) * 2304
                     + 2 * Dm + h * 64 + lc;
#pragma unroll
    for (int i = 0; i < 16; ++i)
        tile[grp * 16 + i][lc] = src[(size_t)i * 2304];
    __syncthreads();
    short* dsth = vth + ((size_t)bh * 64 + grp * 16) * Sc + s0 + lc;
    short* dstl = vtl + ((size_t)bh * 64 + grp * 16) * Sc + s0 + lc;
#pragma unroll
    for (int i = 0; i < 16; ++i) {
        float v = tile[lc][grp * 16 + i];
        short hh = f2bf(v);
        dsth[(size_t)i * Sc] = hh;
        dstl[(size_t)i * Sc] = f2bf(v - bf2f(hh));
    }
}

// ---------------------------------------------------------------------------
// MFMA flash-attention partial (r12 version: 3 blocks/CU, pure-copy V stage
// from pre-split planes; r13's 1-barrier dbuf variant was neutral -> reverted).
__global__ __launch_bounds__(256, 3) void attn_mfma_kernel(
    const float* __restrict__ qkv,
    const short* __restrict__ kph, const short* __restrict__ kpl,
    const short* __restrict__ vth, const short* __restrict__ vtl,
    float* __restrict__ po, float* __restrict__ pm, float* __restrict__ pl)
{
    __shared__ __attribute__((aligned(16))) short VhS[4096];  // V A-frags hi
    __shared__ __attribute__((aligned(16))) short VlS[4096];  // V A-frags lo
    __shared__ __attribute__((aligned(16))) short PhS[8192];  // per-wave P B-frags hi
    __shared__ __attribute__((aligned(16))) short PlS[8192];  // per-wave P B-frags lo

    const int tid = threadIdx.x, lane = tid & 63, wid = tid >> 6;
    const int quad = lane >> 4, l15 = lane & 15;
    const int bh = blockIdx.y;              // b*Hc + h
    const int b = bh / Hc, h = bh % Hc;
    const int chunk = blockIdx.z;
    const int qg = blockIdx.x * 128 + wid * 32;   // wave q base within S
    const int kvb = chunk * 512;
    const int wbase = wid * 2048;

    // Q B-frags (persist in regs): q = qg + nt*16 + l15, d = ks*32 + quad*8 + j
    bf16x8 qh[2][2], ql[2][2];
#pragma unroll
    for (int nt = 0; nt < 2; ++nt) {
        const float* qp = qkv + ((size_t)(b * Sc + qg + nt * 16 + l15)) * 2304
                        + h * 64 + quad * 8;
#pragma unroll
        for (int ks = 0; ks < 2; ++ks) {
            float4 f0 = *(const float4*)(qp + ks * 32);
            float4 f1 = *(const float4*)(qp + ks * 32 + 4);
            float v[8] = {f0.x * 0.125f, f0.y * 0.125f, f0.z * 0.125f, f0.w * 0.125f,
                          f1.x * 0.125f, f1.y * 0.125f, f1.z * 0.125f, f1.w * 0.125f};
            split8v(v, qh[nt][ks], ql[nt][ks]);
        }
    }

    f32x4 oacc[4][2];                       // O^T: [mtd (d)][nt (q)]
#pragma unroll
    for (int i = 0; i < 4; ++i)
#pragma unroll
        for (int j = 0; j < 2; ++j) oacc[i][j] = (f32x4){0.f, 0.f, 0.f, 0.f};
    float mrun[2] = {-1e30f, -1e30f}, lrun[2] = {0.f, 0.f};

    for (int t = 0; t < 8; ++t) {
        const int kv0 = kvb + t * 64;
        __syncthreads();                    // prev tile's V fully consumed
        // ---- stage V tile into A-frag order (pure copy from V^T planes)
#pragma unroll
        for (int it = 0; it < 2; ++it) {
            int slot = tid + it * 256;      // 0..511: frag(ks*4+mtd) x lane
            int f = slot >> 6, ln = slot & 63;
            int sks = f >> 2, smtd = f & 3;
            int sl15 = ln & 15, squad = ln >> 4;
            size_t va = ((size_t)bh * 64 + smtd * 16 + sl15) * Sc
                      + kv0 + sks * 32 + squad * 8;
            *(bf16x8*)&VhS[slot * 8] = *(const bf16x8*)&vth[va];
            *(bf16x8*)&VlS[slot * 8] = *(const bf16x8*)&vtl[va];
        }
        // ---- QK^T: S^T[kv][q], K frags direct from pre-split planes
        f32x4 sacc[4][2];
#pragma unroll
        for (int i = 0; i < 4; ++i)
#pragma unroll
            for (int j = 0; j < 2; ++j) sacc[i][j] = (f32x4){0.f, 0.f, 0.f, 0.f};
#pragma unroll
        for (int ks = 0; ks < 2; ++ks) {
            bf16x8 kh[4], kl[4];
#pragma unroll
            for (int mt = 0; mt < 4; ++mt) {
                const size_t ka = (size_t)(b * Sc + kv0 + mt * 16 + l15) * 768
                                + h * 64 + ks * 32 + quad * 8;
                kh[mt] = *(const bf16x8*)&kph[ka];
                kl[mt] = *(const bf16x8*)&kpl[ka];
            }
#pragma unroll
            for (int mt = 0; mt < 4; ++mt)
#pragma unroll
                for (int nt = 0; nt < 2; ++nt) {
                    sacc[mt][nt] = __builtin_amdgcn_mfma_f32_16x16x32_bf16(kh[mt], qh[nt][ks], sacc[mt][nt], 0, 0, 0);
                    sacc[mt][nt] = __builtin_amdgcn_mfma_f32_16x16x32_bf16(kh[mt], ql[nt][ks], sacc[mt][nt], 0, 0, 0);
                    sacc[mt][nt] = __builtin_amdgcn_mfma_f32_16x16x32_bf16(kl[mt], qh[nt][ks], sacc[mt][nt], 0, 0, 0);
                }
        }
        __syncthreads();                    // V LDS ready for all waves
        // ---- online softmax (row = q; reduce over regs + quads)
#pragma unroll
        for (int nt = 0; nt < 2; ++nt) {
            float mx = -1e30f;
#pragma unroll
            for (int mt = 0; mt < 4; ++mt)
#pragma unroll
                for (int r = 0; r < 4; ++r) mx = fmaxf(mx, sacc[mt][nt][r]);
            mx = fmaxf(mx, __shfl_xor(mx, 16, 64));
            mx = fmaxf(mx, __shfl_xor(mx, 32, 64));
            float nm = fmaxf(mrun[nt], mx);
            float sf = __expf(mrun[nt] - nm);
            mrun[nt] = nm;
            float ladd = 0.f;
#pragma unroll
            for (int mt = 0; mt < 4; ++mt)
#pragma unroll
                for (int r = 0; r < 4; ++r) {
                    float p = __expf(sacc[mt][nt][r] - nm);
                    sacc[mt][nt][r] = p;
                    ladd += p;
                }
            ladd += __shfl_xor(ladd, 16, 64);
            ladd += __shfl_xor(ladd, 32, 64);
            lrun[nt] = lrun[nt] * sf + ladd;
#pragma unroll
            for (int mtd = 0; mtd < 4; ++mtd)
#pragma unroll
                for (int r = 0; r < 4; ++r) oacc[mtd][nt][r] *= sf;
        }
        // ---- P -> LDS (own wave region; B-frag order; short4 = 4 consec kv)
#pragma unroll
        for (int mt = 0; mt < 4; ++mt)
#pragma unroll
            for (int nt = 0; nt < 2; ++nt) {
                short4 ph, pw;
                float p0 = sacc[mt][nt][0], p1 = sacc[mt][nt][1];
                float p2 = sacc[mt][nt][2], p3 = sacc[mt][nt][3];
                ph.x = f2bf(p0); pw.x = f2bf(p0 - bf2f(ph.x));
                ph.y = f2bf(p1); pw.y = f2bf(p1 - bf2f(ph.y));
                ph.z = f2bf(p2); pw.z = f2bf(p2 - bf2f(ph.z));
                ph.w = f2bf(p3); pw.w = f2bf(p3 - bf2f(ph.w));
                int idx = wbase + ((mt >> 1) * 2 + nt) * 512
                        + (((mt & 1) * 2 + (quad >> 1)) * 16 + l15) * 8
                        + (quad & 1) * 4;
                *(short4*)&PhS[idx] = ph;
                *(short4*)&PlS[idx] = pw;
            }
        // ---- PV: O^T += V^T @ P^T (V from LDS; P same-wave LDS)
#pragma unroll
        for (int ks = 0; ks < 2; ++ks) {
            bf16x8 vh[4], vl[4], pbh[2], pbl[2];
#pragma unroll
            for (int mtd = 0; mtd < 4; ++mtd) {
                int va = (ks * 4 + mtd) * 512 + lane * 8;
                vh[mtd] = *(const bf16x8*)&VhS[va];
                vl[mtd] = *(const bf16x8*)&VlS[va];
            }
#pragma unroll
            for (int nt = 0; nt < 2; ++nt) {
                int pa = wbase + (ks * 2 + nt) * 512 + lane * 8;
                pbh[nt] = *(const bf16x8*)&PhS[pa];
                pbl[nt] = *(const bf16x8*)&PlS[pa];
            }
#pragma unroll
            for (int mtd = 0; mtd < 4; ++mtd)
#pragma unroll
                for (int nt = 0; nt < 2; ++nt) {
                    oacc[mtd][nt] = __builtin_amdgcn_mfma_f32_16x16x32_bf16(vh[mtd], pbh[nt], oacc[mtd][nt], 0, 0, 0);
                    oacc[mtd][nt] = __builtin_amdgcn_mfma_f32_16x16x32_bf16(vh[mtd], pbl[nt], oacc[mtd][nt], 0, 0, 0);
                    oacc[mtd][nt] = __builtin_amdgcn_mfma_f32_16x16x32_bf16(vl[mtd], pbh[nt], oacc[mtd][nt], 0, 0, 0);
                }
        }
    }

    // ---- epilogue: O^T lane holds 4 consecutive d per (mtd,nt) -> float4
    const size_t qrow = (size_t)bh * Sc + qg;
#pragma unroll
    for (int nt = 0; nt < 2; ++nt) {
        float* pob = po + ((size_t)chunk * NQ + qrow + nt * 16 + l15) * 64;
#pragma unroll
        for (int mtd = 0; mtd < 4; ++mtd) {
            float4 o4;
            o4.x = oacc[mtd][nt][0]; o4.y = oacc[mtd][nt][1];
            o4.z = oacc[mtd][nt][2]; o4.w = oacc[mtd][nt][3];
            *(float4*)(pob + mtd * 16 + quad * 4) = o4;
        }
        if (quad == 0) {
            pm[(size_t)chunk * NQ + qrow + nt * 16 + l15] = mrun[nt];
            pl[(size_t)chunk * NQ + qrow + nt * 16 + l15] = lrun[nt];
        }
    }
}

__global__ __launch_bounds__(256) void attn_combine_kernel(
    const float* __restrict__ po, const float* __restrict__ pm,
    const float* __restrict__ pl, float* __restrict__ ao)
{
    const int tid = threadIdx.x;
    const int d = tid & 63;
    const int qi = blockIdx.x * 4 + (tid >> 6);
    const int bh = qi >> 11;
    const int s = qi & (Sc - 1);
    const int b = bh / Hc, h = bh % Hc;
    float m0 = pm[qi], m1 = pm[NQ + qi], m2 = pm[2*NQ + qi], m3 = pm[3*NQ + qi];
    float M = fmaxf(fmaxf(m0, m1), fmaxf(m2, m3));
    float w0 = __expf(m0 - M), w1 = __expf(m1 - M);
    float w2 = __expf(m2 - M), w3 = __expf(m3 - M);
    float l = w0 * pl[qi] + w1 * pl[NQ + qi] + w2 * pl[2*NQ + qi] + w3 * pl[3*NQ + qi];
    float o = w0 * po[(size_t)qi * 64 + d]
            + w1 * po[((size_t)NQ + qi) * 64 + d]
            + w2 * po[((size_t)2*NQ + qi) * 64 + d]
            + w3 * po[((size_t)3*NQ + qi) * 64 + d];
    ao[((size_t)(b * Sc + s)) * Dm + h * 64 + d] = o / l;
}

// ---------------------------------------------------------------------------
__global__ __launch_bounds__(256) void conv_silu_kernel(
    const float* __restrict__ xz, const float* __restrict__ cw,
    const float* __restrict__ cb, float* __restrict__ u)
{
    int id = blockIdx.x * 256 + threadIdx.x;
    int d = id % DI;
    int r = id / DI;
    int s = r & (Sc - 1);
    int b = r >> 11;
    float acc = cb[d];
#pragma unroll
    for (int j = 0; j < 4; ++j) {
        int sp = s + j - 3;
        if (sp >= 0)
            acc += xz[((size_t)(b * Sc + sp)) * (2 * DI) + d] * cw[d * 4 + j];
    }
    u[id] = acc / (1.f + __expf(-acc));
}

// ---------------------------------------------------------------------------
// Segmented parallel scan, coalesced (r5-verified). Block = (b, 16 dd).
__global__ __launch_bounds__(512) void scan_kernel(
    const float* __restrict__ delta, const float* __restrict__ u,
    const float* __restrict__ dbc, const float* __restrict__ A_log,
    const float* __restrict__ Dp, float* __restrict__ y)
{
    constexpr int GDD  = 16;
    constexpr int NSEG = 32;
    constexpr int LSEG = Sc / NSEG;        // 64
    const int tid = threadIdx.x;
    const int ddl = tid & 15;
    const int seg = tid >> 4;              // 0..31
    const int blk = blockIdx.x;            // 0..Bc*(DI/GDD)-1
    const int b = blk / (DI / GDD);
    const int dd0 = (blk % (DI / GDD)) * GDD;
    const int dd = dd0 + ddl;

    float Av[NST];
#pragma unroll
    for (int n = 0; n < NST; ++n) Av[n] = -__expf(A_log[dd * NST + n]);
    const float Dv = Dp[dd];

    const float* dbase = delta + (size_t)b * Sc * DI + dd;
    const float* ubase = u     + (size_t)b * Sc * DI + dd;
    const float* cbase = dbc   + (size_t)b * Sc * 80 + DTR;

    __shared__ float sdtS[NSEG][GDD];
    __shared__ float hendS[NSEG][GDD][NST];
    __shared__ float hstartS[NSEG][GDD][NST];

    const int t0 = seg * LSEG;
    float h[NST];
#pragma unroll
    for (int n = 0; n < NST; ++n) h[n] = 0.f;
    float sdt = 0.f;
#pragma unroll 2
    for (int i = 0; i < LSEG; ++i) {
        size_t t = t0 + i;
        float dt = dbase[t * DI];
        float du = dt * ubase[t * DI];
        sdt += dt;
        const float4* bp = (const float4*)(cbase + t * 80);
        float4 B0 = bp[0], B1 = bp[1], B2 = bp[2], B3 = bp[3];
        float Bv[NST] = {B0.x, B0.y, B0.z, B0.w, B1.x, B1.y, B1.z, B1.w,
                         B2.x, B2.y, B2.z, B2.w, B3.x, B3.y, B3.z, B3.w};
#pragma unroll
        for (int n = 0; n < NST; ++n)
            h[n] = __expf(dt * Av[n]) * h[n] + du * Bv[n];
    }
    sdtS[seg][ddl] = sdt;
#pragma unroll
    for (int n = 0; n < NST; ++n) hendS[seg][ddl][n] = h[n];
    __syncthreads();
    if (tid < GDD * NST) {
        const int cn = tid >> 4;
        const float Avn = Av[cn];
        float hs = 0.f;
#pragma unroll
        for (int s = 0; s < NSEG; ++s) {
            hstartS[s][ddl][cn] = hs;
            hs = __expf(Avn * sdtS[s][ddl]) * hs + hendS[s][ddl][cn];
        }
    }
    __syncthreads();
#pragma unroll
    for (int n = 0; n < NST; ++n) h[n] = hstartS[seg][ddl][n];
    float* yp = y + (size_t)b * Sc * DI + dd;
#pragma unroll 2
    for (int i = 0; i < LSEG; ++i) {
        size_t t = t0 + i;
        float dt = dbase[t * DI];
        float uu = ubase[t * DI];
        float du = dt * uu;
        const float4* bp = (const float4*)(cbase + t * 80);
        float4 B0 = bp[0], B1 = bp[1], B2 = bp[2], B3 = bp[3];
        float4 C0 = bp[4], C1 = bp[5], C2 = bp[6], C3 = bp[7];
        float Bv[NST] = {B0.x, B0.y, B0.z, B0.w, B1.x, B1.y, B1.z, B1.w,
                         B2.x, B2.y, B2.z, B2.w, B3.x, B3.y, B3.z, B3.w};
        float Cv[NST] = {C0.x, C0.y, C0.z, C0.w, C1.x, C1.y, C1.z, C1.w,
                         C2.x, C2.y, C2.z, C2.w, C3.x, C3.y, C3.z, C3.w};
        float p = 0.f;
#pragma unroll
        for (int n = 0; n < NST; ++n) {
            h[n] = __expf(dt * Av[n]) * h[n] + du * Bv[n];
            p += h[n] * Cv[n];
        }
        yp[t * DI] = p + uu * Dv;
    }
}

// ---------------------------------------------------------------------------
__global__ __launch_bounds__(256) void ssmin_kernel(
    float* __restrict__ y, const float* __restrict__ xz)
{
    int id = blockIdx.x * 256 + threadIdx.x;
    int d = id % DI;
    int r = id / DI;
    float z = xz[(size_t)r * (2 * DI) + DI + d];
    y[id] = y[id] * (z / (1.f + __expf(-z)));
}

// ---------------------------------------------------------------------------
__global__ __launch_bounds__(256) void x1_kernel(
    const float* __restrict__ x, const float* __restrict__ g,
    const float* __restrict__ at, const float* __restrict__ sm,
    float* __restrict__ x1)
{
    int id = blockIdx.x * 256 + threadIdx.x;
    float gv = g[id];
    x1[id] = x[id] + gv * at[id] + (1.f - gv) * sm[id];
}

// ---------------------------------------------------------------------------
__global__ __launch_bounds__(256) void rowdot_kernel(
    const float* __restrict__ rh, const float* __restrict__ w2,
    const float* __restrict__ b2, float* __restrict__ sc)
{
    int lane = threadIdx.x & 63;
    int t = blockIdx.x * 4 + (threadIdx.x >> 6);
    const float* rp = rh + (size_t)t * 192;
    float sum = rp[lane] * w2[lane] + rp[lane + 64] * w2[lane + 64]
              + rp[lane + 128] * w2[lane + 128];
#pragma unroll
    for (int off = 32; off; off >>= 1) sum += __shfl_down(sum, off, 64);
    if (lane == 0) sc[t] = sum + b2[0];
}

// ---------------------------------------------------------------------------
// Top-k via in-LDS bitonic sort (r4-verified).
__global__ __launch_bounds__(256) void topk_kernel(
    const float* __restrict__ sc, int* __restrict__ idxb)
{
    __shared__ unsigned long long keys[Sc];   // 16 KB
    const int b = blockIdx.x, tid = threadIdx.x;
    for (int i = tid; i < Sc; i += 256) {
        unsigned u = __float_as_uint(sc[(size_t)b * Sc + i]);
        unsigned ou = (u & 0x80000000u) ? ~u : (u | 0x80000000u);
        keys[i] = ((unsigned long long)ou << 32) | (unsigned)(Sc - 1 - i);
    }
    __syncthreads();
    for (int size = 2; size <= Sc; size <<= 1) {
        for (int stride = size >> 1; stride > 0; stride >>= 1) {
#pragma unroll 4
            for (int t = tid; t < Sc / 2; t += 256) {
                int lo = t & (stride - 1);
                int i = ((t ^ lo) << 1) | lo;
                int j = i | stride;
                bool asc = ((i & size) == 0);
                unsigned long long a = keys[i], c = keys[j];
                if (asc ? (a < c) : (a > c)) { keys[i] = c; keys[j] = a; }
            }
            __syncthreads();
        }
    }
    if (tid < CAP)
        idxb[b * CAP + tid] = Sc - 1 - (int)(keys[tid] & 0xFFFFFFFFu);
}

// ---------------------------------------------------------------------------
__global__ __launch_bounds__(256) void gather_kernel(
    const float* __restrict__ xn2, const int* __restrict__ idxb,
    float* __restrict__ Xsel)
{
    int i = blockIdx.x;
    int b = i >> 8;
    int t = idxb[i];
    const float* src = xn2 + ((size_t)(b * Sc + t)) * Dm;
    float* dst = Xsel + (size_t)i * Dm;
    int c = threadIdx.x;
    dst[c] = src[c]; dst[c + 256] = src[c + 256]; dst[c + 512] = src[c + 512];
}

__global__ __launch_bounds__(256) void finaladd_kernel(
    const float* __restrict__ x1, const float* __restrict__ xn2,
    float* __restrict__ out)
{
    int id = blockIdx.x * 256 + threadIdx.x;
    out[id] = x1[id] + xn2[id];
}

__global__ __launch_bounds__(256) void scatter_kernel(
    const float* __restrict__ x1, const float* __restrict__ proc,
    const int* __restrict__ idxb, float* __restrict__ out)
{
    int i = blockIdx.x;
    int b = i >> 8;
    int t = idxb[i];
    size_t ro = ((size_t)(b * Sc + t)) * Dm;
    const float* pp = proc + (size_t)i * Dm;
    int c = threadIdx.x;
    out[ro + c]       = x1[ro + c]       + pp[c];
    out[ro + c + 256] = x1[ro + c + 256] + pp[c + 256];
    out[ro + c + 512] = x1[ro + c + 512] + pp[c + 512];
}

// ---------------------------------------------------------------------------
extern "C" void kernel_launch(void* const* d_in, const int* in_sizes, int n_in,
                              void* d_out, int out_size, void* d_ws, size_t ws_size,
                              hipStream_t stream)
{
    (void)in_sizes; (void)n_in; (void)out_size; (void)ws_size;
    const float* x          = (const float*)d_in[0];
    const float* ln1_w      = (const float*)d_in[1];
    const float* ln1_b      = (const float*)d_in[2];
    const float* ln2_w      = (const float*)d_in[3];
    const float* ln2_b      = (const float*)d_in[4];
    const float* qkv_w      = (const float*)d_in[5];
    const float* attn_out_w = (const float*)d_in[6];
    const float* attn_out_b = (const float*)d_in[7];
    const float* in_proj_w  = (const float*)d_in[8];
    const float* conv_w     = (const float*)d_in[9];
    const float* conv_b     = (const float*)d_in[10];
    const float* x_proj_w   = (const float*)d_in[11];
    const float* dt_w       = (const float*)d_in[12];
    const float* dt_b       = (const float*)d_in[13];
    const float* A_log      = (const float*)d_in[14];
    const float* Dvec       = (const float*)d_in[15];
    const float* ssm_out_w  = (const float*)d_in[16];
    const float* gate_w     = (const float*)d_in[17];
    const float* gate_b     = (const float*)d_in[18];
    const float* ffn_w1     = (const float*)d_in[19];
    const float* ffn_b1     = (const float*)d_in[20];
    const float* ffn_w2     = (const float*)d_in[21];
    const float* ffn_b2     = (const float*)d_in[22];
    const float* r_w1       = (const float*)d_in[23];
    const float* r_b1       = (const float*)d_in[24];
    const float* r_w2       = (const float*)d_in[25];
    const float* r_b2       = (const float*)d_in[26];
    float* out = (float*)d_out;

    // ---- Layout (floats). End = 53,318,144 floats = 213.27 MB (< 215.24 proven).
    float* ws  = (float*)d_ws;
    float* xn  = ws;                       // TOK           (live 1-6)
    float* ao  = ws + TOK;                 // TOK           (live 4.5-5)
    float* y   = ws;                       // 2*TOK         (live 10-12; xn/ao dead)
    float* qkv = ws + 2 * TOK;             // 9.44M         (live 2-4)
    float* xz  = ws + 2 * TOK;             // 12.58M        (live 6-11; over qkv)
    float* u   = ws + 18874368;            // 6.29M         (live 7-10)
    float* xn2 = ws + 18874368;            // TOK           (live 16+; u dead)
    // pre-split attention planes live 3.5-4, in u's region (u dead until 7):
    short* kph = (short*)(ws + 18874368);  // K hi  [M_,768] = 3.146M shorts
    short* kpl = (short*)(ws + 20447232);  // K lo
    short* vth = (short*)(ws + 22020096);  // V^T hi [bh,64,Sc]
    short* vtl = (short*)(ws + 23592960);  // V^T lo; ends 25165824
    // split-K partials: fp1 in ws base (xn/ao dead at steps 8, 21);
    // fp2 in dead xz region (step 22)
    float* fp1 = ws;                       // up to 2*TOK
    float* fp2 = ws + 2 * TOK;             // 8 x 393,216 = TOK (xz dead)
    float* dbc = ws + 25165824;            // 327,680       (live 8-10)
    float* attn_out = ws + 25493504;       // TOK           (live 5-15)
    float* ssm_out  = ws + 28639232;       // TOK           (live 12-15)
    float* g        = ws + 31784960;       // TOK           (live 13-15)
    float* x1       = ws + 34930688;       // TOK           (live 15+)
    float* po    = attn_out;               // 12.58M        (live 4-4.5; spans 4 slots)
    float* delta = ssm_out;                // 6.29M         (live 9-10; ssm_out+g slots)
    float* rh  = ws + 38076416;            // 786,432       (live 17-18)
    float* pmb = rh + 64;                  // 196,608 (guard gap vs po end)
    float* plb = pmb + (size_t)NCH * NQ;   // 196,608
    float* sc  = ws + 38862848;            // 4,096  -> ends 38,866,944
    int*   idxb = (int*)(ws + 38866944);   // 512 ints = 512 float slots
    float* Xsel = ws + 38867456;           // 393,216 -> ends 39,260,672
    float* Hsel = ws + 39260672;           // 1,572,864 -> ends 40,833,536
    float* proc = ws + 40833536;           // 393,216 -> ends 41,226,752
    short* wb   = (short*)(ws + 41226752); // 24,182,784 shorts (12,091,392 floats)
    short* qkvh = wb,            *qkvl = wb + 1769472;
    short* atth = wb + 3538944,  *attl = wb + 4128768;
    short* inph = wb + 4718592,  *inpl = wb + 7077888;
    short* xpjh = wb + 9437184,  *xpjl = wb + 9633792;
    short* ssmh = wb + 10027008, *ssml = wb + 11206656;
    short* g1h  = wb + 12386304, *g1l  = wb + 12976128;
    short* g2h  = wb + 13565952, *g2l  = wb + 14155776;
    short* f1h  = wb + 14745600, *f1l  = wb + 17104896;
    short* f2h  = wb + 19464192, *f2l  = wb + 21823488;

    // ---- weight pre-swizzles (every launch)
    auto WS = [&](const float* W, short* Wh, short* Wl, int K, int N, int Kp, int Np) {
        int total = Kp * Np;
        wswz_kernel<<<(total + 255) / 256, 256, 0, stream>>>(W, Wh, Wl, K, N, Kp, Np);
    };
    WS(qkv_w, qkvh, qkvl, 768, 2304, 768, 2304);
    WS(attn_out_w, atth, attl, 768, 768, 768, 768);
    WS(in_proj_w, inph, inpl, 768, 3072, 768, 3072);
    WS(x_proj_w, xpjh, xpjl, 1536, 80, 1536, 128);
    WS(ssm_out_w, ssmh, ssml, 1536, 768, 1536, 768);
    WS(gate_w, g1h, g1l, 768, 768, 768, 768);
    WS(gate_w + (size_t)768 * 768, g2h, g2l, 768, 768, 768, 768);
    WS(ffn_w1, f1h, f1l, 768, 3072, 768, 3072);
    WS(ffn_w2, f2h, f2l, 3072, 768, 3072, 768);

    // 1. LN1
    ln_kernel<<<M_, 256, 0, stream>>>(x, ln1_w, ln1_b, xn);
    // 2. QKV
    gemm_bf3<0><<<dim3(18, 32), 256, 0, stream>>>(xn, Dm, qkvh, qkvl, 144,
        nullptr, qkv, M_, 2304, 768, 0, 0);
    // 3. RoPE
    rope_kernel<<<(Bc * Sc * Hc * 32) / 256, 256, 0, stream>>>(qkv);
    // 3.5 pre-split K (post-RoPE) + transpose+split V
    ksplit_kernel<<<(M_ * 96) / 256, 256, 0, stream>>>(qkv, kph, kpl);
    vtrans_kernel<<<Bc * Hc * (Sc / 64), 256, 0, stream>>>(qkv, vth, vtl);
    // 4. attention (MFMA flash partial + combine)
    attn_mfma_kernel<<<dim3(Sc / 128, Bc * Hc, NCH), 256, 0, stream>>>(
        qkv, kph, kpl, vth, vtl, po, pmb, plb);
    attn_combine_kernel<<<NQ / 4, 256, 0, stream>>>(po, pmb, plb, ao);
    // 5. attn_out projection (po dead)
    gemm_bf3<1><<<dim3(6, 32), 256, 0, stream>>>(ao, Dm, atth, attl, 48,
        attn_out_b, attn_out, M_, 768, 768, 0, 0);
    // 6. in_proj (qkv dead; xz overwrites it)
    gemm_bf3<2><<<dim3(24, 32), 256, 0, stream>>>(xn, Dm, inph, inpl, 192,
        nullptr, xz, M_, 3072, 768, 0, 0);
    // 7. conv + SiLU (kph..vtl dead -> u)
    conv_silu_kernel<<<(M_ * DI) / 256, 256, 0, stream>>>(xz, conv_w, conv_b, u);
    // 8. x_proj (N=80, Npad=128) split-K x8: was grid (1,32)=32 blocks with
    //    48 serial K-steps (12.5% of CUs, same disease as r8 FFN2/r9 router).
    //    xn/ao dead -> partials in ws base.
    gemm_bf3_pk<3><<<dim3(1, 32, 8), 256, 0, stream>>>(u, DI, xpjh, xpjl, 8,
        fp1, M_, 80, 192);
    pkreduce_kernel<<<(M_ * 80 + 255) / 256, 256, 0, stream>>>(
        fp1, 8, M_ * 80, 80, nullptr, dbc, 0);
    // 9. delta = softplus(dbc[:,:48] @ dt_w + dt_b), dedicated fp32 kernel
    delta_kernel<<<M_, 256, 0, stream>>>(dbc, dt_w, dt_b, delta);
    // 10. scan -> y (xn/ao dead); coalesced segmented scan, block = (b, 16 dd)
    scan_kernel<<<Bc * (DI / 16), 512, 0, stream>>>(delta, u, dbc, A_log, Dvec, y);
    // 11. y *= silu(z) in place (delta dead after scan)
    ssmin_kernel<<<(M_ * DI) / 256, 256, 0, stream>>>(y, xz);
    // 12. ssm_out
    gemm_bf3<5><<<dim3(6, 32), 256, 0, stream>>>(y, DI, ssmh, ssml, 48,
        nullptr, ssm_out, M_, 768, 1536, 0, 0);
    // 13/14. gate
    gemm_bf3<6><<<dim3(6, 32), 256, 0, stream>>>(attn_out, Dm, g1h, g1l, 48,
        nullptr, g, M_, 768, 768, 0, 0);
    gemm_bf3<7><<<dim3(6, 32), 256, 0, stream>>>(ssm_out, Dm, g2h, g2l, 48,
        gate_b, g, M_, 768, 768, 2, 1);
    // 15. x1
    x1_kernel<<<(M_ * Dm) / 256, 256, 0, stream>>>(x, g, attn_out, ssm_out, x1);
    // 16. LN2 (u dead -> xn2)
    ln_kernel<<<M_, 256, 0, stream>>>(x1, ln2_w, ln2_b, xn2);
    // 17. router (pure fp32, selection-critical; 64x64 tiles, grid 3x64)
    gemm_kernel<8><<<dim3(3, 64), 256, 0, stream>>>(xn2, Dm, r_w1, r_b1, rh, M_, 192, 768, 3, 0);
    // 18. scores
    rowdot_kernel<<<M_ / 4, 256, 0, stream>>>(rh, r_w2, r_b2, sc);
    // 19. top-k (bitonic)
    topk_kernel<<<Bc, 256, 0, stream>>>(sc, idxb);
    // 20. gather
    gather_kernel<<<Bc * CAP, 256, 0, stream>>>(xn2, idxb, Xsel);
    // 21. FFN1 split-K x4 (partials in ws base; y dead after step 12)
    gemm_bf3_pk<9><<<dim3(24, 4, 4), 256, 0, stream>>>(Xsel, Dm, f1h, f1l, 192,
        fp1, Bc * CAP, DF, 192);
    pkreduce_kernel<<<(Bc * CAP * DF) / 256, 256, 0, stream>>>(
        fp1, 4, Bc * CAP * DF, DF, ffn_b1, Hsel, 4);
    // 22. FFN2 split-K x8 (partials in dead xz region)
    gemm_bf3_pk<10><<<dim3(6, 4, 8), 256, 0, stream>>>(Hsel, DF, f2h, f2l, 48,
        fp2, Bc * CAP, 768, 384);
    pkreduce_kernel<<<(Bc * CAP * 768) / 256, 256, 0, stream>>>(
        fp2, 8, Bc * CAP * 768, 768, ffn_b2, proc, 0);
    // 23. out = x1 + xn2
    finaladd_kernel<<<(M_ * Dm) / 256, 256, 0, stream>>>(x1, xn2, out);
    // 24. scatter
    scatter_kernel<<<Bc * CAP, 256, 0, stream>>>(x1, proc, idxb, out);
}